// Round 7
// baseline (15743.018 us; speedup 1.0000x reference)
//
#include <hip/hip_runtime.h>
#include <hip/hip_cooperative_groups.h>
#include <math.h>

namespace cg = cooperative_groups;

#define B_ 8
#define S_ 2
#define L_ 32000
#define T_ 497
#define AE 256
#define NFREQ 129
#define FC 385
#define XSTR 388
#define FRSTR 516
#define AFSTR 516
#define BTL 256
#define H_ 512
#define NB 32
#define EMBED 20
#define KB (T_*FC)
#define MEPS 1e-12f
#define PI2F 6.28318530717958647692f

// ---------------- workspace layout (floats) ----------------
static constexpr size_t ALGN(size_t x){ return (x + 63) & ~(size_t)63; }
static constexpr size_t o_bfr  = 0;                                   // 256*516
static constexpr size_t o_decB = ALGN(o_bfr + (size_t)256*516);       // 514*256
static constexpr size_t o_decBias = ALGN(o_decB + (size_t)514*256);   // 256
static constexpr size_t o_biasF  = ALGN(o_decBias + 256);             // 516
static constexpr size_t o_cf   = ALGN(o_biasF + 516);                 // 3976*516
static constexpr size_t o_mag  = ALGN(o_cf + (size_t)B_*T_*FRSTR);
static constexpr size_t o_cosp = ALGN(o_mag + (size_t)B_*T_*NFREQ);
static constexpr size_t o_sinp = ALGN(o_cosp + (size_t)B_*T_*NFREQ);
static constexpr size_t o_xln  = ALGN(o_sinp + (size_t)B_*T_*NFREQ);
static constexpr size_t o_x    = ALGN(o_xln + (size_t)B_*T_*XSTR);
static constexpr size_t o_y    = ALGN(o_x + (size_t)B_*T_*BTL);
static constexpr size_t o_z    = ALGN(o_y + (size_t)B_*T_*H_);
static constexpr size_t o_gsum = ALGN(o_z + (size_t)B_*T_*H_);   // 32 blocks * 32 floats
static constexpr size_t o_acc  = o_gsum + 1024;                  // B*16*21 = 2688
static constexpr size_t o_att  = ALGN(o_acc + (size_t)B_*16*21);
static constexpr size_t o_emb  = ALGN(o_att + (size_t)B_*2*EMBED);
static constexpr size_t o_Af   = ALGN(o_emb + (size_t)B_*KB*EMBED);  // 7952*516
static constexpr size_t o_fr   = o_y;   // alias: ybuf dead before dec GEMM (same size)

// ---------------- setup: combined frame-basis, decoder basis, biases --------
__global__ __launch_bounds__(256) void k_prep(const float* __restrict__ enc_w,
                                              const float* __restrict__ enc_b,
                                              const float* __restrict__ dec_w,
                                              const float* __restrict__ dec_b,
                                              float* __restrict__ bfr,
                                              float* __restrict__ decB,
                                              float* __restrict__ decBias,
                                              float* __restrict__ biasF){
  int i = blockIdx.x*256 + threadIdx.x;
  if (i < 256*516){
    int k = i / 516, n = i % 516;
    float v;
    if (n < 256) v = enc_w[(size_t)k*256 + n];
    else if (n < 514){
      int f2 = n - 256;
      float win = sqrtf(0.5f - 0.5f*cosf(PI2F * (float)k / 256.0f));
      int f = (f2 < NFREQ) ? f2 : (f2 - NFREQ);
      int m = (k * f) & 255;
      float th = PI2F * (float)m / 256.0f;
      v = (f2 < NFREQ) ? win * cosf(th) : -win * sinf(th);
    } else v = 0.f;
    bfr[i] = v;
    return;
  }
  int j = i - 256*516;
  if (j < 514*256){
    int k = j / 256, n = j & 255;
    float v;
    if (k < 256){
      v = 0.5f * dec_w[(size_t)k*256 + n];
    } else {
      int m = n & 63;
      float den = 0.f;
      #pragma unroll
      for (int q = 0; q < 4; q++) den += 0.5f - 0.5f*cosf(PI2F*(float)(m + 64*q)/256.0f);
      float win = sqrtf(0.5f - 0.5f*cosf(PI2F*(float)n/256.0f));
      float iw = win / den;
      int f = (k < 385) ? (k - 256) : (k - 385);
      int mm = (f * n) & 255;
      float th = PI2F * (float)mm / 256.0f;
      if (k < 385){
        float cf = (f==0 || f==128) ? 1.0f : 2.0f;
        v = 0.5f * iw * cf * cosf(th) * (1.0f/256.0f);
      } else {
        v = (f==0 || f==128) ? 0.0f : -1.0f * iw * sinf(th) * (1.0f/256.0f);
      }
    }
    decB[j] = v;
    return;
  }
  int jj = j - 514*256;
  if (jj < 256){ decBias[jj] = 0.5f * dec_b[jj]; return; }
  int n = jj - 256;
  if (n < 516) biasF[n] = (n < 256) ? enc_b[n] : 0.f;
}

// ---------------- pipelined 64x64 GEMM (non-TCN uses) ----------------
// ALOAD: 0 plain A; 2 A = summed audio frames
// EPI:   0 bias (+relu for c<relu_cols)
template<int ALOAD, int EPI, bool BUNIF>
__global__ __launch_bounds__(256, 2) void gemm3(
    const float* __restrict__ A, const float* __restrict__ Bm,
    const float* __restrict__ bias, float* __restrict__ C,
    int M, int N, int K, int lda, int ldb,
    const float* __restrict__ aff_g, const float* __restrict__ aff_b,
    const float* __restrict__ gsumIn,
    const float* __restrict__ prelu_a, float* __restrict__ gsumOut,
    const float* __restrict__ resid, int relu_cols)
{
  __shared__ float As[16][68];
  __shared__ float Bs[16][68];
  const int tid = threadIdx.x;
  const int tx = tid & 15, ty = tid >> 4;
  const int row0 = blockIdx.y*64, col0 = blockIdx.x*64;
  const int am = tid >> 2, ak = (tid & 3)*4;
  const int bk = tid >> 4, bn = (tid & 15)*4;
  const int arow = row0 + am;
  const bool aok = arow < M;
  const float* aptr = nullptr;
  const float* ap0 = nullptr; const float* ap1 = nullptr;
  if (ALOAD == 2){
    int r = aok ? arow : 0;
    int b = r / T_, t = r % T_;
    ap0 = A + ((size_t)b*2)*L_ + t*64;
    ap1 = ap0 + L_;
  } else {
    aptr = A + (size_t)(aok ? arow : 0)*lda;
  }
  const bool bfull = (col0 + 64 <= N);
  const int ksteps = (K+15) >> 4;

  float4 av, bv;

#define LOADA(ks_) { int k0 = (ks_) << 4; \
    av = make_float4(0.f,0.f,0.f,0.f); \
    if (aok){ \
      if (ALOAD == 2){ \
        float4 u = *(const float4*)(ap0 + k0 + ak); \
        float4 w = *(const float4*)(ap1 + k0 + ak); \
        av.x = u.x+w.x; av.y = u.y+w.y; av.z = u.z+w.z; av.w = u.w+w.w; \
      } else if (k0 + ak + 4 <= lda){ \
        av = *(const float4*)(aptr + k0 + ak); \
      } else { \
        float* pv = (float*)&av; \
        for (int j = 0; j < 4; j++){ int k = k0+ak+j; if (k < K) pv[j] = aptr[k]; } \
      } \
    } }

#define LOADB(ks_) { int k = ((ks_) << 4) + bk; \
    bv = make_float4(0.f,0.f,0.f,0.f); \
    if (k < K){ \
      if (bfull) bv = *(const float4*)(Bm + (size_t)k*ldb + col0 + bn); \
      else { float* pv = (float*)&bv; \
        for (int j = 0; j < 4; j++){ int c = col0+bn+j; if (c < N) pv[j] = Bm[(size_t)k*ldb + c]; } } } }

  float acc[4][4] = {};
  LOADA(0); LOADB(0);
  for (int ks = 0; ks < ksteps; ks++){
    As[ak+0][am] = av.x; As[ak+1][am] = av.y;
    As[ak+2][am] = av.z; As[ak+3][am] = av.w;
    *(float4*)&Bs[bk][bn] = bv;
    __syncthreads();
    if (ks + 1 < ksteps){ LOADA(ks+1); LOADB(ks+1); }
    #pragma unroll
    for (int kk = 0; kk < 16; kk++){
      float a4[4], b4[4];
      *(float4*)a4 = *(const float4*)&As[kk][ty*4];
      *(float4*)b4 = *(const float4*)&Bs[kk][tx*4];
      #pragma unroll
      for (int i = 0; i < 4; i++)
        #pragma unroll
        for (int j = 0; j < 4; j++) acc[i][j] = fmaf(a4[i], b4[j], acc[i][j]);
    }
    __syncthreads();
  }
#undef LOADA
#undef LOADB

  float bb4[4];
  #pragma unroll
  for (int j = 0; j < 4; j++){
    int c = col0 + tx*4 + j;
    bb4[j] = (bias && c < N) ? bias[c] : 0.f;
  }
  #pragma unroll
  for (int i = 0; i < 4; i++){
    int r_l = row0 + ty*4 + i;
    if (r_l >= M) continue;
    size_t r_g = (size_t)r_l;
    int c0 = col0 + tx*4;
    if (bfull){
      float4 o; float* po = (float*)&o;
      #pragma unroll
      for (int j = 0; j < 4; j++){
        float v = acc[i][j] + bb4[j];
        if (c0 + j < relu_cols) v = fmaxf(v, 0.f);
        po[j] = v;
      }
      *(float4*)(C + r_g*N + c0) = o;
    } else {
      #pragma unroll
      for (int j = 0; j < 4; j++){
        int c = c0 + j;
        if (c >= N) continue;
        float v = acc[i][j] + bb4[j];
        if (c < relu_cols) v = fmaxf(v, 0.f);
        C[r_g*N + c] = v;
      }
    }
  }
}

// ---------------- 128x64 f32 GEMM (separator only) -------
template<int ALOAD, int EPI, bool BUNIF>
__global__ __launch_bounds__(256) void gemm2(
    const float* __restrict__ A, const float* __restrict__ Bm,
    const float* __restrict__ bias, float* __restrict__ C,
    int M, int N, int K, int lda,
    const float* __restrict__ aff_g, const float* __restrict__ aff_b,
    const float* __restrict__ gsumIn,
    const float* __restrict__ prelu_a, float* __restrict__ gsumOut,
    const float* __restrict__ resid)
{
  __shared__ float As[16][132];
  __shared__ float Bs[16][68];
  const int tid = threadIdx.x;
  const int tx = tid & 15, ty = tid >> 4;
  const int row0 = blockIdx.y * 128, col0 = blockIdx.x * 64;
  const int am  = tid >> 2;
  const int akg = (tid & 3) * 4;
  const int bk  = tid >> 4, bn = (tid & 15) * 4;

  const float* aptr[2]; bool aok[2];
  #pragma unroll
  for (int i = 0; i < 2; i++){
    int r_l = row0 + am + 64*i;
    aok[i] = (r_l < M);
    aptr[i] = A + (size_t)(aok[i] ? r_l : 0) * lda;
  }
  const bool bfull = (col0 + 64 <= N);

  float acc[8][4] = {};
  const int ksteps = (K + 15) >> 4;
  for (int ks = 0; ks < ksteps; ks++){
    const int k0 = ks << 4;
    #pragma unroll
    for (int i = 0; i < 2; i++){
      float4 v = make_float4(0.f, 0.f, 0.f, 0.f);
      float* pv = (float*)&v;
      if (aok[i]){
        if (k0 + akg + 4 <= lda) v = *(const float4*)(aptr[i] + k0 + akg);
        else {
          #pragma unroll
          for (int j = 0; j < 4; j++){ int k = k0+akg+j; if (k < K) pv[j] = aptr[i][k]; }
        }
      }
      #pragma unroll
      for (int j = 0; j < 4; j++) As[akg+j][am + 64*i] = pv[j];
    }
    {
      float4 v = make_float4(0.f, 0.f, 0.f, 0.f);
      float* pv = (float*)&v;
      int k = k0 + bk;
      if (k < K){
        if (bfull) v = *(const float4*)(Bm + (size_t)k*N + col0 + bn);
        else {
          #pragma unroll
          for (int j = 0; j < 4; j++){ int c = col0+bn+j; if (c < N) pv[j] = Bm[(size_t)k*N + c]; }
        }
      }
      *(float4*)&Bs[bk][bn] = v;
    }
    __syncthreads();
    #pragma unroll
    for (int kk = 0; kk < 16; kk++){
      float av[8], bv[4];
      #pragma unroll
      for (int i = 0; i < 8; i++) av[i] = As[kk][ty*8+i];
      #pragma unroll
      for (int j = 0; j < 4; j++) bv[j] = Bs[kk][tx*4+j];
      #pragma unroll
      for (int i = 0; i < 8; i++)
        #pragma unroll
        for (int j = 0; j < 4; j++) acc[i][j] = fmaf(av[i], bv[j], acc[i][j]);
    }
    __syncthreads();
  }
  float bb[4];
  #pragma unroll
  for (int j = 0; j < 4; j++){
    int c = col0 + tx*4 + j;
    bb[j] = (bias && c < N) ? bias[c] : 0.f;
  }
  #pragma unroll
  for (int i = 0; i < 8; i++){
    int r_l = row0 + ty*8 + i;
    if (r_l >= M) continue;
    size_t r_g = (size_t)r_l;
    int c0 = col0 + tx*4;
    if (bfull){
      float4 o; float* po = (float*)&o;
      #pragma unroll
      for (int j = 0; j < 4; j++) po[j] = acc[i][j] + bb[j];
      *(float4*)(C + r_g*N + c0) = o;
    } else {
      #pragma unroll
      for (int j = 0; j < 4; j++){
        int c = c0 + j;
        if (c >= N) continue;
        C[r_g*N + c] = acc[i][j] + bb[j];
      }
    }
  }
}

// ================= cooperative fused TCN =================
struct SMem {
  float As[16][36];
  float Bs[16][68];
  float red[8];
};

__device__ __forceinline__ void c1_tile(SMem& sm, const float* __restrict__ X,
    const float* __restrict__ Bm, const float* __restrict__ bias,
    const float* __restrict__ pa, float* __restrict__ Y, float* __restrict__ gs,
    int b, int mt, int nt, int tid)
{
  const int tx = tid & 15, ty = tid >> 4;
  const int row0 = mt*32, col0 = nt*64;
  const int am = tid >> 3, ak = (tid & 7)*2;
  const int bk = tid >> 4, bn = (tid & 15)*4;
  const int arow = row0 + am;
  const bool aok = arow < T_;
  const float* aptr = X + ((size_t)b*T_ + (aok ? arow : 0))*BTL;
  float2 av = make_float2(0.f, 0.f);
  if (aok) av = *(const float2*)(aptr + ak);
  float4 bv = *(const float4*)(Bm + (size_t)bk*H_ + col0 + bn);
  float acc[2][4] = {};
  for (int ks = 0; ks < 16; ks++){
    sm.As[ak][am] = av.x; sm.As[ak+1][am] = av.y;
    *(float4*)&sm.Bs[bk][bn] = bv;
    __syncthreads();
    if (ks + 1 < 16){
      int k0 = (ks+1) << 4;
      if (aok) av = *(const float2*)(aptr + k0 + ak);
      bv = *(const float4*)(Bm + (size_t)(k0+bk)*H_ + col0 + bn);
    }
    #pragma unroll
    for (int kk = 0; kk < 16; kk++){
      float a2[2], b4[4];
      a2[0] = sm.As[kk][ty*2]; a2[1] = sm.As[kk][ty*2+1];
      *(float4*)b4 = *(const float4*)&sm.Bs[kk][tx*4];
      #pragma unroll
      for (int i = 0; i < 2; i++)
        #pragma unroll
        for (int j = 0; j < 4; j++) acc[i][j] = fmaf(a2[i], b4[j], acc[i][j]);
    }
    __syncthreads();
  }
  float bb4[4], pa4[4];
  #pragma unroll
  for (int j = 0; j < 4; j++){
    int c = col0 + tx*4 + j;
    bb4[j] = bias[c]; pa4[j] = pa[c];
  }
  float ps = 0.f, pss = 0.f;
  #pragma unroll
  for (int i = 0; i < 2; i++){
    int r = row0 + ty*2 + i;
    if (r < T_){
      float4 o; float* po = (float*)&o;
      #pragma unroll
      for (int j = 0; j < 4; j++){
        float v = acc[i][j] + bb4[j];
        float p = fmaxf(v, 0.f) + pa4[j]*fminf(v, 0.f);
        po[j] = p; ps += p; pss += p*p;
      }
      *(float4*)(Y + ((size_t)b*T_ + r)*H_ + col0 + tx*4) = o;
    }
  }
  #pragma unroll
  for (int off = 32; off > 0; off >>= 1){
    ps  += __shfl_down(ps, off);
    pss += __shfl_down(pss, off);
  }
  if ((tid & 63) == 0){ sm.red[(tid>>6)*2] = ps; sm.red[(tid>>6)*2+1] = pss; }
  __syncthreads();
  if (tid == 0){
    atomicAdd(&gs[b*2],   sm.red[0]+sm.red[2]+sm.red[4]+sm.red[6]);
    atomicAdd(&gs[b*2+1], sm.red[1]+sm.red[3]+sm.red[5]+sm.red[7]);
  }
  __syncthreads();
}

__device__ __forceinline__ void dw_row(SMem& sm, const float* __restrict__ Y,
    const float* __restrict__ dwk, const float* __restrict__ gg,
    const float* __restrict__ gb, const float* __restrict__ gs1,
    const float* __restrict__ pa, float* __restrict__ Z,
    float* __restrict__ gs2, int dil, int b, int t, int tid)
{
  const float icnt = 1.f/((float)T_*(float)H_);
  float m = gs1[b*2]*icnt;
  float rstd = rsqrtf(gs1[b*2+1]*icnt - m*m + MEPS);
  float ps = 0.f, pss = 0.f;
  #pragma unroll
  for (int cc = 0; cc < 2; cc++){
    int c = tid + cc*256;
    float g = gg[c] * rstd;
    float bb = gb[c] - m * g;
    float z = 0.f;
    #pragma unroll
    for (int kk = 0; kk < 3; kk++){
      int tt = t + (kk-1)*dil;
      if (tt >= 0 && tt < T_){
        float p = Y[((size_t)b*T_ + tt)*H_ + c];
        z += dwk[kk*H_ + c] * (p*g + bb);
      }
    }
    float p2 = fmaxf(z, 0.f) + pa[c]*fminf(z, 0.f);
    Z[((size_t)b*T_ + t)*H_ + c] = p2;
    ps += p2; pss += p2*p2;
  }
  #pragma unroll
  for (int off = 32; off > 0; off >>= 1){
    ps  += __shfl_down(ps, off);
    pss += __shfl_down(pss, off);
  }
  if ((tid & 63) == 0){ sm.red[(tid>>6)*2] = ps; sm.red[(tid>>6)*2+1] = pss; }
  __syncthreads();
  if (tid == 0){
    atomicAdd(&gs2[b*2],   sm.red[0]+sm.red[2]+sm.red[4]+sm.red[6]);
    atomicAdd(&gs2[b*2+1], sm.red[1]+sm.red[3]+sm.red[5]+sm.red[7]);
  }
  __syncthreads();
}

__device__ __forceinline__ void c2_tile(SMem& sm, const float* __restrict__ Z,
    const float* __restrict__ Bm, const float* __restrict__ bias,
    const float* __restrict__ gg, const float* __restrict__ gb,
    const float* __restrict__ gs, float* __restrict__ X,
    int mt, int nt, int tid)
{
  const int tx = tid & 15, ty = tid >> 4;
  const int row0 = mt*32, col0 = nt*64;
  const int am = tid >> 3, ak = (tid & 7)*2;
  const int bk = tid >> 4, bn = (tid & 15)*4;
  const int arow = row0 + am;
  const bool aok = arow < B_*T_;
  const int grow = aok ? arow : 0;
  const float* aptr = Z + (size_t)grow * H_;
  const int b = grow / T_;
  const float icnt = 1.f/((float)T_*(float)H_);
  float m = gs[b*2]*icnt;
  float rstd = rsqrtf(gs[b*2+1]*icnt - m*m + MEPS);
  float2 av = make_float2(0.f, 0.f), ag, abv;
  if (aok) av = *(const float2*)(aptr + ak);
  ag  = *(const float2*)(gg + ak);
  abv = *(const float2*)(gb + ak);
  float4 bv = *(const float4*)(Bm + (size_t)bk*BTL + col0 + bn);
  float acc[2][4] = {};
  for (int ks = 0; ks < 32; ks++){
    sm.As[ak][am]   = (av.x - m)*rstd*ag.x + abv.x;
    sm.As[ak+1][am] = (av.y - m)*rstd*ag.y + abv.y;
    *(float4*)&sm.Bs[bk][bn] = bv;
    __syncthreads();
    if (ks + 1 < 32){
      int k0 = (ks+1) << 4;
      if (aok) av = *(const float2*)(aptr + k0 + ak);
      ag  = *(const float2*)(gg + k0 + ak);
      abv = *(const float2*)(gb + k0 + ak);
      bv  = *(const float4*)(Bm + (size_t)(k0+bk)*BTL + col0 + bn);
    }
    #pragma unroll
    for (int kk = 0; kk < 16; kk++){
      float a2[2], b4[4];
      a2[0] = sm.As[kk][ty*2]; a2[1] = sm.As[kk][ty*2+1];
      *(float4*)b4 = *(const float4*)&sm.Bs[kk][tx*4];
      #pragma unroll
      for (int i = 0; i < 2; i++)
        #pragma unroll
        for (int j = 0; j < 4; j++) acc[i][j] = fmaf(a2[i], b4[j], acc[i][j]);
    }
    __syncthreads();
  }
  float bb4[4];
  #pragma unroll
  for (int j = 0; j < 4; j++) bb4[j] = bias[col0 + tx*4 + j];
  #pragma unroll
  for (int i = 0; i < 2; i++){
    int r = row0 + ty*2 + i;
    if (r < B_*T_){
      float* xp = X + (size_t)r*BTL + col0 + tx*4;
      float4 rv = *(const float4*)xp;
      float* pr = (float*)&rv;
      float4 o; float* po = (float*)&o;
      #pragma unroll
      for (int j = 0; j < 4; j++) po[j] = acc[i][j] + bb4[j] + pr[j];
      *(float4*)xp = o;
    }
  }
}

__global__ __launch_bounds__(256, 4) void k_tcn(
    float* xbuf, float* ybuf, float* zbuf, float* gsum,
    const float* c1_w, const float* c1_b, const float* p1,
    const float* g1_g, const float* g1_b, const float* dwp,
    const float* p2, const float* g2_g, const float* g2_b,
    const float* c2_w, const float* c2_b)
{
  cg::grid_group grid = cg::this_grid();
  __shared__ SMem sm;
  const int tid = threadIdx.x;
  const int nb = gridDim.x;
  for (int i = 0; i < NB; i++){
    const int dil = 1 << (i & 7);
    // stage 1: c1 (M=497/b 32-row tiles x 8 N-tiles x 8 b = 1024 tiles)
    for (int tile = blockIdx.x; tile < 1024; tile += nb){
      int b = tile >> 7, mt = (tile >> 3) & 15, nt = tile & 7;
      c1_tile(sm, xbuf, c1_w + (size_t)i*BTL*H_, c1_b + i*H_, p1 + i*H_,
              ybuf, gsum + i*32, b, mt, nt, tid);
    }
    grid.sync();
    // stage 2: depthwise conv rows
    for (int r = blockIdx.x; r < B_*T_; r += nb){
      dw_row(sm, ybuf, dwp + (size_t)i*3*H_, g1_g + i*H_, g1_b + i*H_,
             gsum + i*32, p2 + i*H_, zbuf, gsum + i*32 + 16, dil,
             r / T_, r % T_, tid);
    }
    grid.sync();
    // stage 3: c2 (+gLN-affine on load, +residual) 125 x 4 = 500 tiles
    for (int tile = blockIdx.x; tile < 500; tile += nb){
      int mt = tile >> 2, nt = tile & 3;
      c2_tile(sm, zbuf, c2_w + (size_t)i*H_*BTL, c2_b + i*BTL,
              g2_g + i*H_, g2_b + i*H_, gsum + i*32 + 16, xbuf, mt, nt, tid);
    }
    grid.sync();
  }
}

// ---------------- cLN over [enc | log1p(mag)] ----------------
__global__ __launch_bounds__(256) void k_cln(
    const float* __restrict__ cf,
    const float* __restrict__ gamma, const float* __restrict__ beta,
    float* __restrict__ mag, float* __restrict__ cosp, float* __restrict__ sinp,
    float* __restrict__ xln){
  int t = blockIdx.x, b = blockIdx.y, tid = threadIdx.x;
  size_t row = (size_t)b*T_ + t;
  __shared__ float feat[FC];
  __shared__ float red[8];
  feat[tid] = cf[row*FRSTR + tid];
  if (tid < NFREQ){
    float re = cf[row*FRSTR + 256 + tid], im = cf[row*FRSTR + 385 + tid];
    float m = sqrtf(re*re + im*im);
    mag[row*NFREQ + tid] = m;
    float c = 1.f, s = 0.f;
    if (m > 0.f){ c = re/m; s = im/m; }
    cosp[row*NFREQ + tid] = c;
    sinp[row*NFREQ + tid] = s;
    feat[AE + tid] = log1pf(m);
  }
  __syncthreads();
  float v = feat[tid] + ((tid < FC-256) ? feat[256+tid] : 0.f);
  #pragma unroll
  for (int off = 32; off > 0; off >>= 1) v += __shfl_down(v, off);
  if ((tid & 63) == 0) red[tid>>6] = v;
  __syncthreads();
  float mean = (red[0]+red[1]+red[2]+red[3]) * (1.0f/FC);
  float d0 = feat[tid] - mean;
  float vv = d0*d0;
  if (tid < FC-256){ float d1 = feat[256+tid] - mean; vv += d1*d1; }
  __syncthreads();
  #pragma unroll
  for (int off = 32; off > 0; off >>= 1) vv += __shfl_down(vv, off);
  if ((tid & 63) == 0) red[tid>>6] = vv;
  __syncthreads();
  float var = (red[0]+red[1]+red[2]+red[3]) * (1.0f/FC);
  float rstd = rsqrtf(var + MEPS);
  xln[row*XSTR + tid] = (feat[tid]-mean)*rstd*gamma[tid] + beta[tid];
  if (tid < FC-256)
    xln[row*XSTR + 256+tid] = (feat[256+tid]-mean)*rstd*gamma[256+tid] + beta[256+tid];
  if (tid < XSTR-FC) xln[row*XSTR + FC + tid] = 0.f;
}

// ---------------- attractor accumulation (register accumulators) ------------
#define ATTR_CH 16
__global__ __launch_bounds__(256) void k_attr2(const float* __restrict__ emb,
                                               const float* __restrict__ anchors,
                                               float* __restrict__ acc){
  const int c0a[16] = {0,0,0,0,0,1,1,1,1,2,2,2,3,3,4,0};
  const int c1a[16] = {1,2,3,4,5,2,3,4,5,3,4,5,4,5,5,0};
  int by = blockIdx.y;
  int b = by >> 2, g = by & 3;
  int tid = threadIdx.x;
  __shared__ float anc[6][20];
  __shared__ float wred[4][84];
  if (tid < 120) anc[tid/20][tid%20] = anchors[tid];
  __syncthreads();
  float ar[4][21];
  #pragma unroll
  for (int q = 0; q < 4; q++)
    #pragma unroll
    for (int e = 0; e < 21; e++) ar[q][e] = 0.f;
  const float* eb = emb + (size_t)b*KB*EMBED;
  for (int k = blockIdx.x*256 + tid; k < KB; k += ATTR_CH*256){
    float e[20];
    const float4* p = (const float4*)(eb + (size_t)k*EMBED);
    #pragma unroll
    for (int i = 0; i < 5; i++){
      float4 v = p[i];
      e[4*i] = v.x; e[4*i+1] = v.y; e[4*i+2] = v.z; e[4*i+3] = v.w;
    }
    float d[6];
    #pragma unroll
    for (int c = 0; c < 6; c++){
      float s = 0.f;
      #pragma unroll
      for (int j = 0; j < 20; j++) s = fmaf(e[j], anc[c][j], s);
      d[c] = s;
    }
    #pragma unroll
    for (int q = 0; q < 4; q++){
      int s = g*4 + q;
      float w = (s == 15) ? 1.0f : 1.0f / (1.0f + expf(d[c1a[s]] - d[c0a[s]]));
      #pragma unroll
      for (int j = 0; j < 20; j++) ar[q][j] = fmaf(w, e[j], ar[q][j]);
      ar[q][20] += w;
    }
  }
  #pragma unroll
  for (int q = 0; q < 4; q++)
    #pragma unroll
    for (int e = 0; e < 21; e++)
      #pragma unroll
      for (int off = 32; off > 0; off >>= 1)
        ar[q][e] += __shfl_down(ar[q][e], off);
  if ((tid & 63) == 0){
    int w = tid >> 6;
    #pragma unroll
    for (int q = 0; q < 4; q++)
      #pragma unroll
      for (int e = 0; e < 21; e++) wred[w][q*21+e] = ar[q][e];
  }
  __syncthreads();
  if (tid < 84){
    float s = wred[0][tid] + wred[1][tid] + wred[2][tid] + wred[3][tid];
    int q = tid / 21, e = tid % 21;
    atomicAdd(&acc[((size_t)b*16 + g*4 + q)*21 + e], s);
  }
}

// ---------------- attractor normalize + select ----------------
__global__ __launch_bounds__(128) void k_attrfin2(const float* __restrict__ acc,
                                                  float* __restrict__ attractors){
  __shared__ float aN[120][40];
  __shared__ float sp[120];
  int tid = threadIdx.x;
  if (tid < 120){
    int b = tid / 15, p = tid % 15;
    const float* ap = acc + ((size_t)b*16 + p)*21;
    const float* ae = acc + ((size_t)b*16 + 15)*21;
    float den0 = ap[20];
    float den1 = (float)KB - den0;
    float s = 0.f;
    for (int e = 0; e < 20; e++){
      float a0 = ap[e] / den0;
      float a1 = (ae[e] - ap[e]) / den1;
      aN[tid][e] = a0; aN[tid][20+e] = a1;
      s = fmaf(a0, a1, s);
    }
    sp[tid] = s;
  }
  __syncthreads();
  if (tid < B_){
    int base = tid * 15, best = 0;
    float bv = sp[base];
    for (int p = 1; p < 15; p++) if (sp[base+p] < bv){ bv = sp[base+p]; best = p; }
    for (int i = 0; i < 40; i++) attractors[tid*40 + i] = aN[base+best][i];
  }
}

// ---------------- build decoder-GEMM A rows (stride 516, pads zeroed) -------
__global__ __launch_bounds__(256) void k_afull(
    const float* __restrict__ emb, const float* __restrict__ cf,
    const float* __restrict__ mag, const float* __restrict__ cosp,
    const float* __restrict__ sinp, const float* __restrict__ attractors,
    float* __restrict__ Af){
  int t = blockIdx.x, b = blockIdx.y, tid = threadIdx.x;
  __shared__ float att[40];
  if (tid < 40) att[tid] = attractors[b*40 + tid];
  __syncthreads();
  size_t row = (size_t)b*T_ + t;
  size_t r0 = ((size_t)(b*2+0)*T_ + t)*AFSTR;
  size_t r1 = ((size_t)(b*2+1)*T_ + t)*AFSTR;
  for (int f = tid; f < FC; f += 256){
    const float* e = emb + (row*FC + f)*20;
    float l0 = 0.f, l1 = 0.f;
    #pragma unroll
    for (int j = 0; j < 20; j++){
      float ev = e[j];
      l0 = fmaf(ev, att[j],    l0);
      l1 = fmaf(ev, att[20+j], l1);
    }
    if (f < AE){
      float ft = cf[row*FRSTR + f];
      Af[r0 + f] = l0*ft;
      Af[r1 + f] = l1*ft;
    } else {
      int fi = f - AE;
      float ft = mag[row*NFREQ + fi];
      float c = cosp[row*NFREQ + fi], s = sinp[row*NFREQ + fi];
      float s0 = l0*ft, s1v = l1*ft;
      Af[r0 + 256 + fi] = c*s0;  Af[r0 + 385 + fi] = s*s0;
      Af[r1 + 256 + fi] = c*s1v; Af[r1 + 385 + fi] = s*s1v;
    }
  }
  if (tid < 2){
    Af[r0 + 514 + tid] = 0.f;
    Af[r1 + 514 + tid] = 0.f;
  }
}

// ---------------- overlap-add gather ----------------
__global__ __launch_bounds__(256) void k_ola(const float* __restrict__ frames,
                                             float* __restrict__ out){
  int i = blockIdx.x*256 + threadIdx.x;
  if (i < B_*2*L_){
    int bs = i / L_, l = i % L_;
    int t0 = l >> 6;
    float s = 0.f;
    #pragma unroll
    for (int j = 0; j < 4; j++){
      int t = t0 - j;
      if (t >= 0 && t < T_){
        int k = l - t*64;
        s += frames[((size_t)bs*T_ + t)*256 + k];
      }
    }
    out[i] = s;
  }
}

// ---------------- launcher ----------------
extern "C" void kernel_launch(void* const* d_in, const int* in_sizes, int n_in,
                              void* d_out, int out_size, void* d_ws, size_t ws_size,
                              hipStream_t stream) {
  const float* audios   = (const float*)d_in[0];
  const float* enc_w    = (const float*)d_in[1];
  const float* enc_b    = (const float*)d_in[2];
  const float* bgamma   = (const float*)d_in[3];
  const float* bbeta    = (const float*)d_in[4];
  const float* bottle_w = (const float*)d_in[5];
  const float* bottle_b = (const float*)d_in[6];
  const float* c1_w     = (const float*)d_in[7];
  const float* c1_b     = (const float*)d_in[8];
  const float* p1       = (const float*)d_in[9];
  const float* g1_g     = (const float*)d_in[10];
  const float* g1_b     = (const float*)d_in[11];
  const float* dwp      = (const float*)d_in[12];
  const float* p2       = (const float*)d_in[13];
  const float* g2_g     = (const float*)d_in[14];
  const float* g2_b     = (const float*)d_in[15];
  const float* c2_w     = (const float*)d_in[16];
  const float* c2_b     = (const float*)d_in[17];
  const float* sep_w    = (const float*)d_in[18];
  const float* sep_b    = (const float*)d_in[19];
  const float* anchors  = (const float*)d_in[20];
  const float* dec_w    = (const float*)d_in[21];
  const float* dec_b    = (const float*)d_in[22];

  float* ws = (float*)d_ws;
  float* bfr   = ws + o_bfr;
  float* decB  = ws + o_decB;
  float* decBias = ws + o_decBias;
  float* biasF = ws + o_biasF;
  float* cf    = ws + o_cf;
  float* mag   = ws + o_mag;
  float* cosp  = ws + o_cosp;
  float* sinp  = ws + o_sinp;
  float* xln   = ws + o_xln;
  float* xbuf  = ws + o_x;
  float* ybuf  = ws + o_y;
  float* zbuf  = ws + o_z;
  float* gsum  = ws + o_gsum;
  float* accp  = ws + o_acc;
  float* attp  = ws + o_att;
  float* embp  = ws + o_emb;
  float* Afull = ws + o_Af;
  float* framesp = ws + o_fr;

  // zero atomic accumulators (gsum 1024 + attr acc 2688, contiguous)
  hipMemsetAsync((void*)gsum, 0, (1024 + (size_t)B_*16*21) * sizeof(float), stream);

  k_prep<<<(256*516 + 514*256 + 256 + 516 + 255)/256, 256, 0, stream>>>(
      enc_w, enc_b, dec_w, dec_b, bfr, decB, decBias, biasF);

  // frames GEMM: mix-on-load, [enc | spec] out, M=3976, N=516, K=256
  gemm3<2,0,false><<<dim3(9, 63), 256, 0, stream>>>(
      audios, bfr, biasF, cf, B_*T_, FRSTR, 256, 0, FRSTR,
      nullptr, nullptr, nullptr, nullptr, nullptr, nullptr, 256);

  k_cln<<<dim3(T_, B_), 256, 0, stream>>>(cf, bgamma, bbeta, mag, cosp, sinp, xln);

  // bottleneck: M=3976, N=256, K=385 (lda=388, zero-padded)
  gemm3<0,0,false><<<dim3(4, 63), 256, 0, stream>>>(
      xln, bottle_w, bottle_b, xbuf, B_*T_, BTL, FC, XSTR, BTL,
      nullptr, nullptr, nullptr, nullptr, nullptr, nullptr, 0);

  // fused TCN: one cooperative kernel, 96 grid-syncs instead of 96 launches
  {
    int maxb = 0;
    hipOccupancyMaxActiveBlocksPerMultiprocessor(&maxb, k_tcn, 256, 0);
    if (maxb < 1) maxb = 1;
    int G = maxb * 256;
    if (G > 1024) G = 1024;
    void* args[] = {(void*)&xbuf, (void*)&ybuf, (void*)&zbuf, (void*)&gsum,
                    (void*)&c1_w, (void*)&c1_b, (void*)&p1,
                    (void*)&g1_g, (void*)&g1_b, (void*)&dwp,
                    (void*)&p2, (void*)&g2_g, (void*)&g2_b,
                    (void*)&c2_w, (void*)&c2_b};
    hipLaunchCooperativeKernel((const void*)k_tcn, dim3(G), dim3(256),
                               args, 0, stream);
  }

  // separator: M=3976, N=7700, K=256 (128-row tiles)
  gemm2<0,0,false><<<dim3(121, 32), 256, 0, stream>>>(
      xbuf, sep_w, sep_b, embp, B_*T_, FC*EMBED, BTL, BTL,
      nullptr, nullptr, nullptr, nullptr, nullptr, nullptr);

  // attractors
  k_attr2<<<dim3(ATTR_CH, B_*4), 256, 0, stream>>>(embp, anchors, accp);
  k_attrfin2<<<1, 128, 0, stream>>>(accp, attp);

  // decode: M=7952, N=256, K=514 (lda=516, zero-padded)
  k_afull<<<dim3(T_, B_), 256, 0, stream>>>(embp, cf, mag, cosp, sinp, attp, Afull);
  gemm3<0,0,false><<<dim3(4, 125), 256, 0, stream>>>(
      Afull, decB, decBias, framesp, 2*B_*T_, 256, 514, AFSTR, BTL,
      nullptr, nullptr, nullptr, nullptr, nullptr, nullptr, 0);
  k_ola<<<(B_*2*L_ + 255)/256, 256, 0, stream>>>(framesp, (float*)d_out);
}

// Round 8
// 5112.239 us; speedup vs baseline: 3.0795x; 3.0795x over previous
//
#include <hip/hip_runtime.h>
#include <math.h>

#define B_ 8
#define S_ 2
#define L_ 32000
#define T_ 497
#define AE 256
#define NFREQ 129
#define FC 385
#define XSTR 388
#define FRSTR 516
#define AFSTR 516
#define BTL 256
#define H_ 512
#define NB 32
#define EMBED 20
#define KB (T_*FC)
#define MEPS 1e-12f
#define PI2F 6.28318530717958647692f

typedef __attribute__((ext_vector_type(8))) short bf16x8;
typedef __attribute__((ext_vector_type(4))) float f32x4;

__device__ __forceinline__ ushort f2bf(float f){
  union { float f; unsigned u; } x; x.f = f;
  unsigned r = x.u + 0x7FFFu + ((x.u >> 16) & 1u);
  return (ushort)(r >> 16);
}
__device__ __forceinline__ float bf2f(ushort h){
  union { unsigned u; float f; } x; x.u = ((unsigned)h) << 16;
  return x.f;
}

// ---------------- workspace layout (float units) ----------------
static constexpr size_t ALGN(size_t x){ return (x + 63) & ~(size_t)63; }
static constexpr size_t o_bfr  = 0;                                   // 256*516
static constexpr size_t o_decB = ALGN(o_bfr + (size_t)256*516);       // 514*256
static constexpr size_t o_decBias = ALGN(o_decB + (size_t)514*256);   // 256
static constexpr size_t o_biasF  = ALGN(o_decBias + 256);             // 516
static constexpr size_t o_cf   = ALGN(o_biasF + 516);                 // 3976*516
static constexpr size_t o_mag  = ALGN(o_cf + (size_t)B_*T_*FRSTR);
static constexpr size_t o_cosp = ALGN(o_mag + (size_t)B_*T_*NFREQ);
static constexpr size_t o_sinp = ALGN(o_cosp + (size_t)B_*T_*NFREQ);
static constexpr size_t o_xln  = ALGN(o_sinp + (size_t)B_*T_*NFREQ);
static constexpr size_t o_x    = ALGN(o_xln + (size_t)B_*T_*XSTR);
static constexpr size_t o_y    = ALGN(o_x + (size_t)B_*T_*BTL);      // holds zb16 then framesp
static constexpr size_t o_z    = ALGN(o_y + (size_t)B_*T_*H_);       // holds yb16
static constexpr size_t o_gsum = ALGN(o_z + (size_t)B_*T_*H_);       // 32*32
static constexpr size_t o_acc  = o_gsum + 1024;                      // B*16*21
static constexpr size_t o_att  = ALGN(o_acc + (size_t)B_*16*21);
static constexpr size_t o_emb  = ALGN(o_att + (size_t)B_*2*EMBED);
static constexpr size_t o_Af   = ALGN(o_emb + (size_t)B_*KB*EMBED);  // 7952*516
static constexpr size_t o_w1p  = ALGN(o_Af + (size_t)2*B_*T_*AFSTR); // 32*131072 ush = 2097152 f
static constexpr size_t o_w2p  = ALGN(o_w1p + (size_t)2097152);
static constexpr size_t o_c1c2 = ALGN(o_w2p + (size_t)2097152);      // 32*512
static constexpr size_t o_xb16 = ALGN(o_c1c2 + (size_t)32*512);      // 4096*256 ush = 524288 f
static constexpr size_t o_fr   = o_y;

// ---------------- setup: combined frame-basis, decoder basis, biases --------
__global__ __launch_bounds__(256) void k_prep(const float* __restrict__ enc_w,
                                              const float* __restrict__ enc_b,
                                              const float* __restrict__ dec_w,
                                              const float* __restrict__ dec_b,
                                              float* __restrict__ bfr,
                                              float* __restrict__ decB,
                                              float* __restrict__ decBias,
                                              float* __restrict__ biasF){
  int i = blockIdx.x*256 + threadIdx.x;
  if (i < 256*516){
    int k = i / 516, n = i % 516;
    float v;
    if (n < 256) v = enc_w[(size_t)k*256 + n];
    else if (n < 514){
      int f2 = n - 256;
      float win = sqrtf(0.5f - 0.5f*cosf(PI2F * (float)k / 256.0f));
      int f = (f2 < NFREQ) ? f2 : (f2 - NFREQ);
      int m = (k * f) & 255;
      float th = PI2F * (float)m / 256.0f;
      v = (f2 < NFREQ) ? win * cosf(th) : -win * sinf(th);
    } else v = 0.f;
    bfr[i] = v;
    return;
  }
  int j = i - 256*516;
  if (j < 514*256){
    int k = j / 256, n = j & 255;
    float v;
    if (k < 256){
      v = 0.5f * dec_w[(size_t)k*256 + n];
    } else {
      int m = n & 63;
      float den = 0.f;
      #pragma unroll
      for (int q = 0; q < 4; q++) den += 0.5f - 0.5f*cosf(PI2F*(float)(m + 64*q)/256.0f);
      float win = sqrtf(0.5f - 0.5f*cosf(PI2F*(float)n/256.0f));
      float iw = win / den;
      int f = (k < 385) ? (k - 256) : (k - 385);
      int mm = (f * n) & 255;
      float th = PI2F * (float)mm / 256.0f;
      if (k < 385){
        float cf = (f==0 || f==128) ? 1.0f : 2.0f;
        v = 0.5f * iw * cf * cosf(th) * (1.0f/256.0f);
      } else {
        v = (f==0 || f==128) ? 0.0f : -1.0f * iw * sinf(th) * (1.0f/256.0f);
      }
    }
    decB[j] = v;
    return;
  }
  int jj = j - 514*256;
  if (jj < 256){ decBias[jj] = 0.5f * dec_b[jj]; return; }
  int n = jj - 256;
  if (n < 516) biasF[n] = (n < 256) ? enc_b[n] : 0.f;
}

// ---------------- pack TCN weights into MFMA B-fragment order ----------------
// w1p: per layer [kc(8)][n16(32)][lane(64)][j(8)]  (K=256,N=512)
// w2p: per layer [kc(16)][n16(16)][lane(64)][j(8)] (K=512,N=256), pre-scaled by g2_g[k]
__global__ __launch_bounds__(256) void k_packw(
    const float* __restrict__ c1_w, const float* __restrict__ c2_w,
    const float* __restrict__ g2_g,
    ushort* __restrict__ w1p, ushort* __restrict__ w2p){
  size_t idx = (size_t)blockIdx.x*256 + threadIdx.x;
  const size_t PER = (size_t)32*131072;
  if (idx < PER){
    int i = (int)(idx >> 17);
    int o = (int)(idx & 131071);
    int kc = o >> 14;
    int n16 = (o >> 9) & 31;
    int l = (o >> 3) & 63;
    int j = o & 7;
    int k = kc*32 + (l>>4)*8 + j;
    int n = n16*16 + (l&15);
    w1p[idx] = f2bf(c1_w[((size_t)i*256 + k)*512 + n]);
  } else if (idx < 2*PER){
    size_t o2 = idx - PER;
    int i = (int)(o2 >> 17);
    int o = (int)(o2 & 131071);
    int kc = o >> 13;
    int n16 = (o >> 9) & 15;
    int l = (o >> 3) & 63;
    int j = o & 7;
    int k = kc*32 + (l>>4)*8 + j;
    int n = n16*16 + (l&15);
    w2p[o2] = f2bf(g2_g[(size_t)i*512 + k] * c2_w[((size_t)i*512 + k)*256 + n]);
  }
}

// ---------------- per-layer gLN2 bias-fold: C1[n]=sum g2_b*W2, C2[n]=sum g2_g*W2
__global__ __launch_bounds__(256) void k_bias2(
    const float* __restrict__ c2_w, const float* __restrict__ g2_g,
    const float* __restrict__ g2_b, float* __restrict__ c1c2){
  int i = blockIdx.x;
  int n = threadIdx.x;
  float s1 = 0.f, s2 = 0.f;
  for (int k = 0; k < 512; k++){
    float w = c2_w[((size_t)i*512 + k)*256 + n];
    s1 = fmaf(g2_b[(size_t)i*512 + k], w, s1);
    s2 = fmaf(g2_g[(size_t)i*512 + k], w, s2);
  }
  c1c2[(size_t)i*512 + n]       = s1;
  c1c2[(size_t)i*512 + 256 + n] = s2;
}

// ---------------- pipelined 64x64 GEMM (non-TCN) ----------------
// ALOAD: 0 plain A; 2 A = summed audio frames
template<int ALOAD>
__global__ __launch_bounds__(256, 2) void gemm3(
    const float* __restrict__ A, const float* __restrict__ Bm,
    const float* __restrict__ bias, float* __restrict__ C,
    int M, int N, int K, int lda, int ldb, int relu_cols,
    ushort* __restrict__ bf16dst)
{
  __shared__ float As[16][68];
  __shared__ float Bs[16][68];
  const int tid = threadIdx.x;
  const int tx = tid & 15, ty = tid >> 4;
  const int row0 = blockIdx.y*64, col0 = blockIdx.x*64;
  const int am = tid >> 2, ak = (tid & 3)*4;
  const int bk = tid >> 4, bn = (tid & 15)*4;
  const int arow = row0 + am;
  const bool aok = arow < M;
  const float* aptr = nullptr;
  const float* ap0 = nullptr; const float* ap1 = nullptr;
  if (ALOAD == 2){
    int r = aok ? arow : 0;
    int b = r / T_, t = r % T_;
    ap0 = A + ((size_t)b*2)*L_ + t*64;
    ap1 = ap0 + L_;
  } else {
    aptr = A + (size_t)(aok ? arow : 0)*lda;
  }
  const bool bfull = (col0 + 64 <= N);
  const int ksteps = (K+15) >> 4;

  float4 av, bv;

#define LOADA(ks_) { int k0 = (ks_) << 4; \
    av = make_float4(0.f,0.f,0.f,0.f); \
    if (aok){ \
      if (ALOAD == 2){ \
        float4 u = *(const float4*)(ap0 + k0 + ak); \
        float4 w = *(const float4*)(ap1 + k0 + ak); \
        av.x = u.x+w.x; av.y = u.y+w.y; av.z = u.z+w.z; av.w = u.w+w.w; \
      } else if (k0 + ak + 4 <= lda){ \
        av = *(const float4*)(aptr + k0 + ak); \
      } else { \
        float* pv = (float*)&av; \
        for (int j = 0; j < 4; j++){ int k = k0+ak+j; if (k < K) pv[j] = aptr[k]; } \
      } \
    } }

#define LOADB(ks_) { int k = ((ks_) << 4) + bk; \
    bv = make_float4(0.f,0.f,0.f,0.f); \
    if (k < K){ \
      if (bfull) bv = *(const float4*)(Bm + (size_t)k*ldb + col0 + bn); \
      else { float* pv = (float*)&bv; \
        for (int j = 0; j < 4; j++){ int c = col0+bn+j; if (c < N) pv[j] = Bm[(size_t)k*ldb + c]; } } } }

  float acc[4][4] = {};
  LOADA(0); LOADB(0);
  for (int ks = 0; ks < ksteps; ks++){
    As[ak+0][am] = av.x; As[ak+1][am] = av.y;
    As[ak+2][am] = av.z; As[ak+3][am] = av.w;
    *(float4*)&Bs[bk][bn] = bv;
    __syncthreads();
    if (ks + 1 < ksteps){ LOADA(ks+1); LOADB(ks+1); }
    #pragma unroll
    for (int kk = 0; kk < 16; kk++){
      float a4[4], b4[4];
      *(float4*)a4 = *(const float4*)&As[kk][ty*4];
      *(float4*)b4 = *(const float4*)&Bs[kk][tx*4];
      #pragma unroll
      for (int i = 0; i < 4; i++)
        #pragma unroll
        for (int j = 0; j < 4; j++) acc[i][j] = fmaf(a4[i], b4[j], acc[i][j]);
    }
    __syncthreads();
  }
#undef LOADA
#undef LOADB

  float bb4[4];
  #pragma unroll
  for (int j = 0; j < 4; j++){
    int c = col0 + tx*4 + j;
    bb4[j] = (bias && c < N) ? bias[c] : 0.f;
  }
  #pragma unroll
  for (int i = 0; i < 4; i++){
    int r_l = row0 + ty*4 + i;
    if (r_l >= M) continue;
    size_t r_g = (size_t)r_l;
    int c0 = col0 + tx*4;
    if (bfull){
      float4 o; float* po = (float*)&o;
      #pragma unroll
      for (int j = 0; j < 4; j++){
        float v = acc[i][j] + bb4[j];
        if (c0 + j < relu_cols) v = fmaxf(v, 0.f);
        po[j] = v;
      }
      *(float4*)(C + r_g*N + c0) = o;
      if (bf16dst){
        #pragma unroll
        for (int j = 0; j < 4; j++) bf16dst[r_g*N + c0 + j] = f2bf(po[j]);
      }
    } else {
      #pragma unroll
      for (int j = 0; j < 4; j++){
        int c = c0 + j;
        if (c >= N) continue;
        float v = acc[i][j] + bb4[j];
        if (c < relu_cols) v = fmaxf(v, 0.f);
        C[r_g*N + c] = v;
        if (bf16dst) bf16dst[r_g*N + c] = f2bf(v);
      }
    }
  }
}

// ---------------- 128x64 f32 GEMM (separator) -------
__global__ __launch_bounds__(256) void gemm2(
    const float* __restrict__ A, const float* __restrict__ Bm,
    const float* __restrict__ bias, float* __restrict__ C,
    int M, int N, int K, int lda)
{
  __shared__ float As[16][132];
  __shared__ float Bs[16][68];
  const int tid = threadIdx.x;
  const int tx = tid & 15, ty = tid >> 4;
  const int row0 = blockIdx.y * 128, col0 = blockIdx.x * 64;
  const int am  = tid >> 2;
  const int akg = (tid & 3) * 4;
  const int bk  = tid >> 4, bn = (tid & 15) * 4;

  const float* aptr[2]; bool aok[2];
  #pragma unroll
  for (int i = 0; i < 2; i++){
    int r_l = row0 + am + 64*i;
    aok[i] = (r_l < M);
    aptr[i] = A + (size_t)(aok[i] ? r_l : 0) * lda;
  }
  const bool bfull = (col0 + 64 <= N);

  float acc[8][4] = {};
  const int ksteps = (K + 15) >> 4;
  for (int ks = 0; ks < ksteps; ks++){
    const int k0 = ks << 4;
    #pragma unroll
    for (int i = 0; i < 2; i++){
      float4 v = make_float4(0.f, 0.f, 0.f, 0.f);
      if (aok[i]) v = *(const float4*)(aptr[i] + k0 + akg);
      #pragma unroll
      for (int j = 0; j < 4; j++) As[akg+j][am + 64*i] = ((float*)&v)[j];
    }
    {
      float4 v = make_float4(0.f, 0.f, 0.f, 0.f);
      float* pv = (float*)&v;
      int k = k0 + bk;
      if (k < K){
        if (bfull) v = *(const float4*)(Bm + (size_t)k*N + col0 + bn);
        else {
          #pragma unroll
          for (int j = 0; j < 4; j++){ int c = col0+bn+j; if (c < N) pv[j] = Bm[(size_t)k*N + c]; }
        }
      }
      *(float4*)&Bs[bk][bn] = v;
    }
    __syncthreads();
    #pragma unroll
    for (int kk = 0; kk < 16; kk++){
      float av[8], bv[4];
      #pragma unroll
      for (int i = 0; i < 8; i++) av[i] = As[kk][ty*8+i];
      #pragma unroll
      for (int j = 0; j < 4; j++) bv[j] = Bs[kk][tx*4+j];
      #pragma unroll
      for (int i = 0; i < 8; i++)
        #pragma unroll
        for (int j = 0; j < 4; j++) acc[i][j] = fmaf(av[i], bv[j], acc[i][j]);
    }
    __syncthreads();
  }
  float bb[4];
  #pragma unroll
  for (int j = 0; j < 4; j++){
    int c = col0 + tx*4 + j;
    bb[j] = (bias && c < N) ? bias[c] : 0.f;
  }
  #pragma unroll
  for (int i = 0; i < 8; i++){
    int r_l = row0 + ty*8 + i;
    if (r_l >= M) continue;
    size_t r_g = (size_t)r_l;
    int c0 = col0 + tx*4;
    if (bfull){
      float4 o; float* po = (float*)&o;
      #pragma unroll
      for (int j = 0; j < 4; j++) po[j] = acc[i][j] + bb[j];
      *(float4*)(C + r_g*N + c0) = o;
    } else {
      #pragma unroll
      for (int j = 0; j < 4; j++){
        int c = c0 + j;
        if (c >= N) continue;
        C[r_g*N + c] = acc[i][j] + bb[j];
      }
    }
  }
}

// ================= MFMA TCN kernels =================
// c1: Y[b*T+t][512] = PReLU(Xb16[b*T+t][256] @ W1 + b1); partial sums -> gs
__global__ __launch_bounds__(256) void k_c1(
    const ushort* __restrict__ xb, const ushort* __restrict__ w1p,
    const float* __restrict__ bias, const float* __restrict__ pa,
    ushort* __restrict__ yb, float* __restrict__ gs)
{
  __shared__ float red[8];
  int tid = threadIdx.x;
  int wv = tid >> 6, l = tid & 63;
  int b = blockIdx.z, mt = blockIdx.y, nb = blockIdx.x;
  int row0 = mt*64 + wv*16;
  int lm = l & 15, lq = l >> 4;
  const ushort* ap = xb + ((size_t)(b*T_ + row0 + lm))*256 + lq*8;
  int n0 = nb*64;
  f32x4 acc[4] = {};
  #pragma unroll
  for (int kc = 0; kc < 8; kc++){
    bf16x8 a = *(const bf16x8*)(ap + kc*32);
    #pragma unroll
    for (int nt = 0; nt < 4; nt++){
      bf16x8 bf = *(const bf16x8*)(w1p + (((size_t)kc*32 + (n0>>4) + nt)*64 + l)*8);
      acc[nt] = __builtin_amdgcn_mfma_f32_16x16x32_bf16(a, bf, acc[nt], 0, 0, 0);
    }
  }
  float ps = 0.f, pss = 0.f;
  #pragma unroll
  for (int nt = 0; nt < 4; nt++){
    int col = n0 + nt*16 + lm;
    float bb = bias[col], pav = pa[col];
    #pragma unroll
    for (int r = 0; r < 4; r++){
      int t = row0 + lq*4 + r;
      if (t < T_){
        float v = acc[nt][r] + bb;
        float p = fmaxf(v, 0.f) + pav*fminf(v, 0.f);
        yb[((size_t)b*T_ + t)*512 + col] = f2bf(p);
        ps += p; pss += p*p;
      }
    }
  }
  #pragma unroll
  for (int off = 32; off > 0; off >>= 1){
    ps  += __shfl_down(ps, off);
    pss += __shfl_down(pss, off);
  }
  if (l == 0){ red[wv*2] = ps; red[wv*2+1] = pss; }
  __syncthreads();
  if (tid == 0) atomicAdd(&gs[b*2],     red[0]+red[2]+red[4]+red[6]);
  if (tid == 1) atomicAdd(&gs[b*2+1],   red[1]+red[3]+red[5]+red[7]);
}

// dw: Z = PReLU2(dwconv(gLN1affine(Y))); stats -> gs2
__global__ __launch_bounds__(256) void k_dw(
    const ushort* __restrict__ yb, const float* __restrict__ dwk,
    const float* __restrict__ gg, const float* __restrict__ gb,
    const float* __restrict__ gs1, const float* __restrict__ pa,
    ushort* __restrict__ zb, float* __restrict__ gs2, int dil)
{
  int t = blockIdx.x, b = blockIdx.y, tid = threadIdx.x;
  const float icnt = 1.f/((float)T_*(float)H_);
  float m = gs1[b*2]*icnt;
  float rstd = rsqrtf(gs1[b*2+1]*icnt - m*m + MEPS);
  __shared__ float red[8];
  int c0 = tid*2;
  float g0 = gg[c0]*rstd, g1v = gg[c0+1]*rstd;
  float b0 = gb[c0] - m*g0, b1 = gb[c0+1] - m*g1v;
  float z0 = 0.f, z1 = 0.f;
  #pragma unroll
  for (int kk = 0; kk < 3; kk++){
    int tt = t + (kk-1)*dil;
    if (tt >= 0 && tt < T_){
      const ushort* yp = yb + ((size_t)b*T_ + tt)*512 + c0;
      float y0 = bf2f(yp[0]), y1 = bf2f(yp[1]);
      z0 += dwk[kk*H_ + c0]     * (y0*g0 + b0);
      z1 += dwk[kk*H_ + c0 + 1] * (y1*g1v + b1);
    }
  }
  float p0 = fmaxf(z0, 0.f) + pa[c0]*fminf(z0, 0.f);
  float p1v = fmaxf(z1, 0.f) + pa[c0+1]*fminf(z1, 0.f);
  ushort2 st; st.x = f2bf(p0); st.y = f2bf(p1v);
  *(ushort2*)(zb + ((size_t)b*T_ + t)*512 + c0) = st;
  float ps = p0 + p1v, pss = p0*p0 + p1v*p1v;
  #pragma unroll
  for (int off = 32; off > 0; off >>= 1){
    ps  += __shfl_down(ps, off);
    pss += __shfl_down(pss, off);
  }
  if ((tid & 63) == 0){ red[(tid>>6)*2] = ps; red[(tid>>6)*2+1] = pss; }
  __syncthreads();
  if (tid == 0){
    atomicAdd(&gs2[b*2],   red[0]+red[2]+red[4]+red[6]);
    atomicAdd(&gs2[b*2+1], red[1]+red[3]+red[5]+red[7]);
  }
}

// c2: X += rstd*(Zb16 @ W2') + C1 - m*rstd*C2 + c2_b ; also write Xb16
__global__ __launch_bounds__(256) void k_c2(
    const ushort* __restrict__ zb, const ushort* __restrict__ w2p,
    const float* __restrict__ c2b, const float* __restrict__ c1c2,
    const float* __restrict__ gs, float* __restrict__ x,
    ushort* __restrict__ xb)
{
  int tid = threadIdx.x;
  int wv = tid >> 6, l = tid & 63;
  int b = blockIdx.z, mt = blockIdx.y, nb = blockIdx.x;
  int row0 = mt*64 + wv*16;
  int lm = l & 15, lq = l >> 4;
  const ushort* ap = zb + ((size_t)(b*T_ + row0 + lm))*512 + lq*8;
  int n0 = nb*64;
  f32x4 acc[4] = {};
  #pragma unroll
  for (int kc = 0; kc < 16; kc++){
    bf16x8 a = *(const bf16x8*)(ap + kc*32);
    #pragma unroll
    for (int nt = 0; nt < 4; nt++){
      bf16x8 bf = *(const bf16x8*)(w2p + (((size_t)kc*16 + (n0>>4) + nt)*64 + l)*8);
      acc[nt] = __builtin_amdgcn_mfma_f32_16x16x32_bf16(a, bf, acc[nt], 0, 0, 0);
    }
  }
  const float icnt = 1.f/((float)T_*(float)H_);
  float m = gs[b*2]*icnt;
  float rstd = rsqrtf(gs[b*2+1]*icnt - m*m + MEPS);
  float mr = m * rstd;
  #pragma unroll
  for (int nt = 0; nt < 4; nt++){
    int col = n0 + nt*16 + lm;
    float cadd = c2b[col] + c1c2[col] - mr*c1c2[256 + col];
    #pragma unroll
    for (int r = 0; r < 4; r++){
      int t = row0 + lq*4 + r;
      if (t < T_){
        size_t off = ((size_t)b*T_ + t)*256 + col;
        float v = rstd*acc[nt][r] + cadd + x[off];
        x[off] = v;
        xb[off] = f2bf(v);
      }
    }
  }
}

// ---------------- cLN over [enc | log1p(mag)] ----------------
__global__ __launch_bounds__(256) void k_cln(
    const float* __restrict__ cf,
    const float* __restrict__ gamma, const float* __restrict__ beta,
    float* __restrict__ mag, float* __restrict__ cosp, float* __restrict__ sinp,
    float* __restrict__ xln){
  int t = blockIdx.x, b = blockIdx.y, tid = threadIdx.x;
  size_t row = (size_t)b*T_ + t;
  __shared__ float feat[FC];
  __shared__ float red[8];
  feat[tid] = cf[row*FRSTR + tid];
  if (tid < NFREQ){
    float re = cf[row*FRSTR + 256 + tid], im = cf[row*FRSTR + 385 + tid];
    float m = sqrtf(re*re + im*im);
    mag[row*NFREQ + tid] = m;
    float c = 1.f, s = 0.f;
    if (m > 0.f){ c = re/m; s = im/m; }
    cosp[row*NFREQ + tid] = c;
    sinp[row*NFREQ + tid] = s;
    feat[AE + tid] = log1pf(m);
  }
  __syncthreads();
  float v = feat[tid] + ((tid < FC-256) ? feat[256+tid] : 0.f);
  #pragma unroll
  for (int off = 32; off > 0; off >>= 1) v += __shfl_down(v, off);
  if ((tid & 63) == 0) red[tid>>6] = v;
  __syncthreads();
  float mean = (red[0]+red[1]+red[2]+red[3]) * (1.0f/FC);
  float d0 = feat[tid] - mean;
  float vv = d0*d0;
  if (tid < FC-256){ float d1 = feat[256+tid] - mean; vv += d1*d1; }
  __syncthreads();
  #pragma unroll
  for (int off = 32; off > 0; off >>= 1) vv += __shfl_down(vv, off);
  if ((tid & 63) == 0) red[tid>>6] = vv;
  __syncthreads();
  float var = (red[0]+red[1]+red[2]+red[3]) * (1.0f/FC);
  float rstd = rsqrtf(var + MEPS);
  xln[row*XSTR + tid] = (feat[tid]-mean)*rstd*gamma[tid] + beta[tid];
  if (tid < FC-256)
    xln[row*XSTR + 256+tid] = (feat[256+tid]-mean)*rstd*gamma[256+tid] + beta[256+tid];
  if (tid < XSTR-FC) xln[row*XSTR + FC + tid] = 0.f;
}

// ---------------- attractor accumulation ------------
#define ATTR_CH 16
__global__ __launch_bounds__(256) void k_attr2(const float* __restrict__ emb,
                                               const float* __restrict__ anchors,
                                               float* __restrict__ acc){
  const int c0a[16] = {0,0,0,0,0,1,1,1,1,2,2,2,3,3,4,0};
  const int c1a[16] = {1,2,3,4,5,2,3,4,5,3,4,5,4,5,5,0};
  int by = blockIdx.y;
  int b = by >> 2, g = by & 3;
  int tid = threadIdx.x;
  __shared__ float anc[6][20];
  __shared__ float wred[4][84];
  if (tid < 120) anc[tid/20][tid%20] = anchors[tid];
  __syncthreads();
  float ar[4][21];
  #pragma unroll
  for (int q = 0; q < 4; q++)
    #pragma unroll
    for (int e = 0; e < 21; e++) ar[q][e] = 0.f;
  const float* eb = emb + (size_t)b*KB*EMBED;
  for (int k = blockIdx.x*256 + tid; k < KB; k += ATTR_CH*256){
    float e[20];
    const float4* p = (const float4*)(eb + (size_t)k*EMBED);
    #pragma unroll
    for (int i = 0; i < 5; i++){
      float4 v = p[i];
      e[4*i] = v.x; e[4*i+1] = v.y; e[4*i+2] = v.z; e[4*i+3] = v.w;
    }
    float d[6];
    #pragma unroll
    for (int c = 0; c < 6; c++){
      float s = 0.f;
      #pragma unroll
      for (int j = 0; j < 20; j++) s = fmaf(e[j], anc[c][j], s);
      d[c] = s;
    }
    #pragma unroll
    for (int q = 0; q < 4; q++){
      int s = g*4 + q;
      float w = (s == 15) ? 1.0f : 1.0f / (1.0f + expf(d[c1a[s]] - d[c0a[s]]));
      #pragma unroll
      for (int j = 0; j < 20; j++) ar[q][j] = fmaf(w, e[j], ar[q][j]);
      ar[q][20] += w;
    }
  }
  #pragma unroll
  for (int q = 0; q < 4; q++)
    #pragma unroll
    for (int e = 0; e < 21; e++)
      #pragma unroll
      for (int off = 32; off > 0; off >>= 1)
        ar[q][e] += __shfl_down(ar[q][e], off);
  if ((tid & 63) == 0){
    int w = tid >> 6;
    #pragma unroll
    for (int q = 0; q < 4; q++)
      #pragma unroll
      for (int e = 0; e < 21; e++) wred[w][q*21+e] = ar[q][e];
  }
  __syncthreads();
  if (tid < 84){
    float s = wred[0][tid] + wred[1][tid] + wred[2][tid] + wred[3][tid];
    int q = tid / 21, e = tid % 21;
    atomicAdd(&acc[((size_t)b*16 + g*4 + q)*21 + e], s);
  }
}

// ---------------- attractor normalize + select ----------------
__global__ __launch_bounds__(128) void k_attrfin2(const float* __restrict__ acc,
                                                  float* __restrict__ attractors){
  __shared__ float aN[120][40];
  __shared__ float sp[120];
  int tid = threadIdx.x;
  if (tid < 120){
    int b = tid / 15, p = tid % 15;
    const float* ap = acc + ((size_t)b*16 + p)*21;
    const float* ae = acc + ((size_t)b*16 + 15)*21;
    float den0 = ap[20];
    float den1 = (float)KB - den0;
    float s = 0.f;
    for (int e = 0; e < 20; e++){
      float a0 = ap[e] / den0;
      float a1 = (ae[e] - ap[e]) / den1;
      aN[tid][e] = a0; aN[tid][20+e] = a1;
      s = fmaf(a0, a1, s);
    }
    sp[tid] = s;
  }
  __syncthreads();
  if (tid < B_){
    int base = tid * 15, best = 0;
    float bv = sp[base];
    for (int p = 1; p < 15; p++) if (sp[base+p] < bv){ bv = sp[base+p]; best = p; }
    for (int i = 0; i < 40; i++) attractors[tid*40 + i] = aN[base+best][i];
  }
}

// ---------------- build decoder-GEMM A rows (stride 516, pads zeroed) -------
__global__ __launch_bounds__(256) void k_afull(
    const float* __restrict__ emb, const float* __restrict__ cf,
    const float* __restrict__ mag, const float* __restrict__ cosp,
    const float* __restrict__ sinp, const float* __restrict__ attractors,
    float* __restrict__ Af){
  int t = blockIdx.x, b = blockIdx.y, tid = threadIdx.x;
  __shared__ float att[40];
  if (tid < 40) att[tid] = attractors[b*40 + tid];
  __syncthreads();
  size_t row = (size_t)b*T_ + t;
  size_t r0 = ((size_t)(b*2+0)*T_ + t)*AFSTR;
  size_t r1 = ((size_t)(b*2+1)*T_ + t)*AFSTR;
  for (int f = tid; f < FC; f += 256){
    const float* e = emb + (row*FC + f)*20;
    float l0 = 0.f, l1 = 0.f;
    #pragma unroll
    for (int j = 0; j < 20; j++){
      float ev = e[j];
      l0 = fmaf(ev, att[j],    l0);
      l1 = fmaf(ev, att[20+j], l1);
    }
    if (f < AE){
      float ft = cf[row*FRSTR + f];
      Af[r0 + f] = l0*ft;
      Af[r1 + f] = l1*ft;
    } else {
      int fi = f - AE;
      float ft = mag[row*NFREQ + fi];
      float c = cosp[row*NFREQ + fi], s = sinp[row*NFREQ + fi];
      float s0 = l0*ft, s1v = l1*ft;
      Af[r0 + 256 + fi] = c*s0;  Af[r0 + 385 + fi] = s*s0;
      Af[r1 + 256 + fi] = c*s1v; Af[r1 + 385 + fi] = s*s1v;
    }
  }
  if (tid < 2){
    Af[r0 + 514 + tid] = 0.f;
    Af[r1 + 514 + tid] = 0.f;
  }
}

// ---------------- overlap-add gather ----------------
__global__ __launch_bounds__(256) void k_ola(const float* __restrict__ frames,
                                             float* __restrict__ out){
  int i = blockIdx.x*256 + threadIdx.x;
  if (i < B_*2*L_){
    int bs = i / L_, l = i % L_;
    int t0 = l >> 6;
    float s = 0.f;
    #pragma unroll
    for (int j = 0; j < 4; j++){
      int t = t0 - j;
      if (t >= 0 && t < T_){
        int k = l - t*64;
        s += frames[((size_t)bs*T_ + t)*256 + k];
      }
    }
    out[i] = s;
  }
}

// ---------------- launcher ----------------
extern "C" void kernel_launch(void* const* d_in, const int* in_sizes, int n_in,
                              void* d_out, int out_size, void* d_ws, size_t ws_size,
                              hipStream_t stream) {
  const float* audios   = (const float*)d_in[0];
  const float* enc_w    = (const float*)d_in[1];
  const float* enc_b    = (const float*)d_in[2];
  const float* bgamma   = (const float*)d_in[3];
  const float* bbeta    = (const float*)d_in[4];
  const float* bottle_w = (const float*)d_in[5];
  const float* bottle_b = (const float*)d_in[6];
  const float* c1_w     = (const float*)d_in[7];
  const float* c1_b     = (const float*)d_in[8];
  const float* p1       = (const float*)d_in[9];
  const float* g1_g     = (const float*)d_in[10];
  const float* g1_b     = (const float*)d_in[11];
  const float* dwp      = (const float*)d_in[12];
  const float* p2       = (const float*)d_in[13];
  const float* g2_g     = (const float*)d_in[14];
  const float* g2_b     = (const float*)d_in[15];
  const float* c2_w     = (const float*)d_in[16];
  const float* c2_b     = (const float*)d_in[17];
  const float* sep_w    = (const float*)d_in[18];
  const float* sep_b    = (const float*)d_in[19];
  const float* anchors  = (const float*)d_in[20];
  const float* dec_w    = (const float*)d_in[21];
  const float* dec_b    = (const float*)d_in[22];

  float* ws = (float*)d_ws;
  float* bfr   = ws + o_bfr;
  float* decB  = ws + o_decB;
  float* decBias = ws + o_decBias;
  float* biasF = ws + o_biasF;
  float* cf    = ws + o_cf;
  float* mag   = ws + o_mag;
  float* cosp  = ws + o_cosp;
  float* sinp  = ws + o_sinp;
  float* xln   = ws + o_xln;
  float* xbuf  = ws + o_x;
  float* gsum  = ws + o_gsum;
  float* accp  = ws + o_acc;
  float* attp  = ws + o_att;
  float* embp  = ws + o_emb;
  float* Afull = ws + o_Af;
  float* framesp = ws + o_fr;
  float* c1c2  = ws + o_c1c2;
  ushort* w1p  = (ushort*)(ws + o_w1p);
  ushort* w2p  = (ushort*)(ws + o_w2p);
  ushort* xb16 = (ushort*)(ws + o_xb16);
  ushort* yb16 = (ushort*)(ws + o_z);
  ushort* zb16 = (ushort*)(ws + o_y);

  // zero atomic accumulators (gsum 1024 + attr acc 2688, contiguous)
  hipMemsetAsync((void*)gsum, 0, (1024 + (size_t)B_*16*21) * sizeof(float), stream);

  k_prep<<<(256*516 + 514*256 + 256 + 516 + 255)/256, 256, 0, stream>>>(
      enc_w, enc_b, dec_w, dec_b, bfr, decB, decBias, biasF);
  k_packw<<<(int)((2u*32u*131072u + 255)/256), 256, 0, stream>>>(
      c1_w, c2_w, g2_g, w1p, w2p);
  k_bias2<<<32, 256, 0, stream>>>(c2_w, g2_g, g2_b, c1c2);

  // frames GEMM: mix-on-load, [enc | spec] out, M=3976, N=516, K=256
  gemm3<2><<<dim3(9, 63), 256, 0, stream>>>(
      audios, bfr, biasF, cf, B_*T_, FRSTR, 256, 0, FRSTR, 256, nullptr);

  k_cln<<<dim3(T_, B_), 256, 0, stream>>>(cf, bgamma, bbeta, mag, cosp, sinp, xln);

  // bottleneck: M=3976, N=256, K=385 (lda=388) ; dual-write x fp32 + bf16
  gemm3<0><<<dim3(4, 63), 256, 0, stream>>>(
      xln, bottle_w, bottle_b, xbuf, B_*T_, BTL, FC, XSTR, BTL, 0, xb16);

  // TCN: MFMA kernels, no LDS staging, weights pre-packed
  for (int i = 0; i < NB; i++){
    int dil = 1 << (i & 7);
    k_c1<<<dim3(8, 8, B_), 256, 0, stream>>>(
        xb16, w1p + (size_t)i*131072, c1_b + i*H_, p1 + i*H_, yb16, gsum + i*32);
    k_dw<<<dim3(T_, B_), 256, 0, stream>>>(
        yb16, dwp + (size_t)i*3*H_, g1_g + i*H_, g1_b + i*H_,
        gsum + i*32, p2 + i*H_, zb16, gsum + i*32 + 16, dil);
    k_c2<<<dim3(4, 8, B_), 256, 0, stream>>>(
        zb16, w2p + (size_t)i*131072, c2_b + i*BTL, c1c2 + (size_t)i*512,
        gsum + i*32 + 16, xbuf, xb16);
  }

  // separator: M=3976, N=7700, K=256
  gemm2<<<dim3(121, 32), 256, 0, stream>>>(
      xbuf, sep_w, sep_b, embp, B_*T_, FC*EMBED, BTL, BTL);

  // attractors
  k_attr2<<<dim3(ATTR_CH, B_*4), 256, 0, stream>>>(embp, anchors, accp);
  k_attrfin2<<<1, 128, 0, stream>>>(accp, attp);

  // decode: M=7952, N=256, K=514 (lda=516, zero-padded)
  k_afull<<<dim3(T_, B_), 256, 0, stream>>>(embp, cf, mag, cosp, sinp, attp, Afull);
  gemm3<0><<<dim3(4, 125), 256, 0, stream>>>(
      Afull, decB, decBias, framesp, 2*B_*T_, 256, 514, AFSTR, BTL, 0, nullptr);
  k_ola<<<(B_*2*L_ + 255)/256, 256, 0, stream>>>(framesp, (float*)d_out);
}

// Round 9
// 2562.076 us; speedup vs baseline: 6.1446x; 1.9954x over previous
//
#include <hip/hip_runtime.h>
#include <math.h>

#define B_ 8
#define S_ 2
#define L_ 32000
#define T_ 497
#define AE 256
#define NFREQ 129
#define FC 385
#define XSTR 388
#define FRSTR 516
#define AFSTR 516
#define BTL 256
#define H_ 512
#define NB 32
#define EMBED 20
#define KB (T_*FC)
#define MEPS 1e-12f
#define PI2F 6.28318530717958647692f

typedef __attribute__((ext_vector_type(8))) short bf16x8;
typedef __attribute__((ext_vector_type(4))) float f32x4;

__device__ __forceinline__ ushort f2bf(float f){
  union { float f; unsigned u; } x; x.f = f;
  unsigned r = x.u + 0x7FFFu + ((x.u >> 16) & 1u);
  return (ushort)(r >> 16);
}
__device__ __forceinline__ float bf2f(ushort h){
  union { unsigned u; float f; } x; x.u = ((unsigned)h) << 16;
  return x.f;
}

// ---------------- workspace layout (float units) ----------------
static constexpr size_t ALGN(size_t x){ return (x + 63) & ~(size_t)63; }
static constexpr size_t o_bfr  = 0;                                   // 256*516
static constexpr size_t o_decB = ALGN(o_bfr + (size_t)256*516);       // 514*256
static constexpr size_t o_decBias = ALGN(o_decB + (size_t)514*256);   // 256
static constexpr size_t o_biasF  = ALGN(o_decBias + 256);             // 516
static constexpr size_t o_cf   = ALGN(o_biasF + 516);                 // 3976*516
static constexpr size_t o_mag  = ALGN(o_cf + (size_t)B_*T_*FRSTR);
static constexpr size_t o_cosp = ALGN(o_mag + (size_t)B_*T_*NFREQ);
static constexpr size_t o_sinp = ALGN(o_cosp + (size_t)B_*T_*NFREQ);
static constexpr size_t o_xln  = ALGN(o_sinp + (size_t)B_*T_*NFREQ);
static constexpr size_t o_x    = ALGN(o_xln + (size_t)B_*T_*XSTR);   // x buf0 (3976*256)
static constexpr size_t o_y    = ALGN(o_x + (size_t)B_*T_*BTL);      // x buf1 + U  (2*3976*256) ; later framesp
static constexpr size_t o_z    = ALGN(o_y + (size_t)B_*T_*H_);       // yb16 (bf16 3976*512 + pad)
static constexpr size_t o_gsum = ALGN(o_z + (size_t)B_*T_*H_);       // 32*32
static constexpr size_t o_acc  = o_gsum + 1024;                      // B*16*21
static constexpr size_t o_att  = ALGN(o_acc + (size_t)B_*16*21);
static constexpr size_t o_emb  = ALGN(o_att + (size_t)B_*2*EMBED);
static constexpr size_t o_Af   = ALGN(o_emb + (size_t)B_*KB*EMBED);  // 7952*516
static constexpr size_t o_w1p  = ALGN(o_Af + (size_t)2*B_*T_*AFSTR); // 32*131072 ush
static constexpr size_t o_w2p  = ALGN(o_w1p + (size_t)2097152);
static constexpr size_t o_c1c2 = ALGN(o_w2p + (size_t)2097152);      // 32*512
static constexpr size_t o_fr   = o_y;

// ---------------- setup: combined frame-basis, decoder basis, biases --------
__global__ __launch_bounds__(256) void k_prep(const float* __restrict__ enc_w,
                                              const float* __restrict__ enc_b,
                                              const float* __restrict__ dec_w,
                                              const float* __restrict__ dec_b,
                                              float* __restrict__ bfr,
                                              float* __restrict__ decB,
                                              float* __restrict__ decBias,
                                              float* __restrict__ biasF){
  int i = blockIdx.x*256 + threadIdx.x;
  if (i < 256*516){
    int k = i / 516, n = i % 516;
    float v;
    if (n < 256) v = enc_w[(size_t)k*256 + n];
    else if (n < 514){
      int f2 = n - 256;
      float win = sqrtf(0.5f - 0.5f*cosf(PI2F * (float)k / 256.0f));
      int f = (f2 < NFREQ) ? f2 : (f2 - NFREQ);
      int m = (k * f) & 255;
      float th = PI2F * (float)m / 256.0f;
      v = (f2 < NFREQ) ? win * cosf(th) : -win * sinf(th);
    } else v = 0.f;
    bfr[i] = v;
    return;
  }
  int j = i - 256*516;
  if (j < 514*256){
    int k = j / 256, n = j & 255;
    float v;
    if (k < 256){
      v = 0.5f * dec_w[(size_t)k*256 + n];
    } else {
      int m = n & 63;
      float den = 0.f;
      #pragma unroll
      for (int q = 0; q < 4; q++) den += 0.5f - 0.5f*cosf(PI2F*(float)(m + 64*q)/256.0f);
      float win = sqrtf(0.5f - 0.5f*cosf(PI2F*(float)n/256.0f));
      float iw = win / den;
      int f = (k < 385) ? (k - 256) : (k - 385);
      int mm = (f * n) & 255;
      float th = PI2F * (float)mm / 256.0f;
      if (k < 385){
        float cf = (f==0 || f==128) ? 1.0f : 2.0f;
        v = 0.5f * iw * cf * cosf(th) * (1.0f/256.0f);
      } else {
        v = (f==0 || f==128) ? 0.0f : -1.0f * iw * sinf(th) * (1.0f/256.0f);
      }
    }
    decB[j] = v;
    return;
  }
  int jj = j - 514*256;
  if (jj < 256){ decBias[jj] = 0.5f * dec_b[jj]; return; }
  int n = jj - 256;
  if (n < 516) biasF[n] = (n < 256) ? enc_b[n] : 0.f;
}

// ---------------- pack TCN weights into MFMA B-fragment order ----------------
__global__ __launch_bounds__(256) void k_packw(
    const float* __restrict__ c1_w, const float* __restrict__ c2_w,
    const float* __restrict__ g2_g,
    ushort* __restrict__ w1p, ushort* __restrict__ w2p){
  size_t idx = (size_t)blockIdx.x*256 + threadIdx.x;
  const size_t PER = (size_t)32*131072;
  if (idx < PER){
    int i = (int)(idx >> 17);
    int o = (int)(idx & 131071);
    int kc = o >> 14;
    int n16 = (o >> 9) & 31;
    int l = (o >> 3) & 63;
    int j = o & 7;
    int k = kc*32 + (l>>4)*8 + j;
    int n = n16*16 + (l&15);
    w1p[idx] = f2bf(c1_w[((size_t)i*256 + k)*512 + n]);
  } else if (idx < 2*PER){
    size_t o2 = idx - PER;
    int i = (int)(o2 >> 17);
    int o = (int)(o2 & 131071);
    int kc = o >> 13;
    int n16 = (o >> 9) & 15;
    int l = (o >> 3) & 63;
    int j = o & 7;
    int k = kc*32 + (l>>4)*8 + j;
    int n = n16*16 + (l&15);
    w2p[o2] = f2bf(g2_g[(size_t)i*512 + k] * c2_w[((size_t)i*512 + k)*256 + n]);
  }
}

// ---------------- per-layer gLN2 bias-fold: C1[n]=sum g2_b*W2, C2[n]=sum g2_g*W2
__global__ __launch_bounds__(256) void k_bias2(
    const float* __restrict__ c2_w, const float* __restrict__ g2_g,
    const float* __restrict__ g2_b, float* __restrict__ c1c2){
  int i = blockIdx.x;
  int n = threadIdx.x;
  float s1 = 0.f, s2 = 0.f;
  for (int k = 0; k < 512; k++){
    float w = c2_w[((size_t)i*512 + k)*256 + n];
    s1 = fmaf(g2_b[(size_t)i*512 + k], w, s1);
    s2 = fmaf(g2_g[(size_t)i*512 + k], w, s2);
  }
  c1c2[(size_t)i*512 + n]       = s1;
  c1c2[(size_t)i*512 + 256 + n] = s2;
}

// ---------------- pipelined 64x64 GEMM (non-TCN) ----------------
template<int ALOAD>
__global__ __launch_bounds__(256, 2) void gemm3(
    const float* __restrict__ A, const float* __restrict__ Bm,
    const float* __restrict__ bias, float* __restrict__ C,
    int M, int N, int K, int lda, int ldb, int relu_cols)
{
  __shared__ float As[16][68];
  __shared__ float Bs[16][68];
  const int tid = threadIdx.x;
  const int tx = tid & 15, ty = tid >> 4;
  const int row0 = blockIdx.y*64, col0 = blockIdx.x*64;
  const int am = tid >> 2, ak = (tid & 3)*4;
  const int bk = tid >> 4, bn = (tid & 15)*4;
  const int arow = row0 + am;
  const bool aok = arow < M;
  const float* aptr = nullptr;
  const float* ap0 = nullptr; const float* ap1 = nullptr;
  if (ALOAD == 2){
    int r = aok ? arow : 0;
    int b = r / T_, t = r % T_;
    ap0 = A + ((size_t)b*2)*L_ + t*64;
    ap1 = ap0 + L_;
  } else {
    aptr = A + (size_t)(aok ? arow : 0)*lda;
  }
  const bool bfull = (col0 + 64 <= N);
  const int ksteps = (K+15) >> 4;

  float4 av, bv;

#define LOADA(ks_) { int k0 = (ks_) << 4; \
    av = make_float4(0.f,0.f,0.f,0.f); \
    if (aok){ \
      if (ALOAD == 2){ \
        float4 u = *(const float4*)(ap0 + k0 + ak); \
        float4 w = *(const float4*)(ap1 + k0 + ak); \
        av.x = u.x+w.x; av.y = u.y+w.y; av.z = u.z+w.z; av.w = u.w+w.w; \
      } else if (k0 + ak + 4 <= lda){ \
        av = *(const float4*)(aptr + k0 + ak); \
      } else { \
        float* pv = (float*)&av; \
        for (int j = 0; j < 4; j++){ int k = k0+ak+j; if (k < K) pv[j] = aptr[k]; } \
      } \
    } }

#define LOADB(ks_) { int k = ((ks_) << 4) + bk; \
    bv = make_float4(0.f,0.f,0.f,0.f); \
    if (k < K){ \
      if (bfull) bv = *(const float4*)(Bm + (size_t)k*ldb + col0 + bn); \
      else { float* pv = (float*)&bv; \
        for (int j = 0; j < 4; j++){ int c = col0+bn+j; if (c < N) pv[j] = Bm[(size_t)k*ldb + c]; } } } }

  float acc[4][4] = {};
  LOADA(0); LOADB(0);
  for (int ks = 0; ks < ksteps; ks++){
    As[ak+0][am] = av.x; As[ak+1][am] = av.y;
    As[ak+2][am] = av.z; As[ak+3][am] = av.w;
    *(float4*)&Bs[bk][bn] = bv;
    __syncthreads();
    if (ks + 1 < ksteps){ LOADA(ks+1); LOADB(ks+1); }
    #pragma unroll
    for (int kk = 0; kk < 16; kk++){
      float a4[4], b4[4];
      *(float4*)a4 = *(const float4*)&As[kk][ty*4];
      *(float4*)b4 = *(const float4*)&Bs[kk][tx*4];
      #pragma unroll
      for (int i = 0; i < 4; i++)
        #pragma unroll
        for (int j = 0; j < 4; j++) acc[i][j] = fmaf(a4[i], b4[j], acc[i][j]);
    }
    __syncthreads();
  }
#undef LOADA
#undef LOADB

  float bb4[4];
  #pragma unroll
  for (int j = 0; j < 4; j++){
    int c = col0 + tx*4 + j;
    bb4[j] = (bias && c < N) ? bias[c] : 0.f;
  }
  #pragma unroll
  for (int i = 0; i < 4; i++){
    int r_l = row0 + ty*4 + i;
    if (r_l >= M) continue;
    size_t r_g = (size_t)r_l;
    int c0 = col0 + tx*4;
    if (bfull){
      float4 o; float* po = (float*)&o;
      #pragma unroll
      for (int j = 0; j < 4; j++){
        float v = acc[i][j] + bb4[j];
        if (c0 + j < relu_cols) v = fmaxf(v, 0.f);
        po[j] = v;
      }
      *(float4*)(C + r_g*N + c0) = o;
    } else {
      #pragma unroll
      for (int j = 0; j < 4; j++){
        int c = c0 + j;
        if (c >= N) continue;
        float v = acc[i][j] + bb4[j];
        if (c < relu_cols) v = fmaxf(v, 0.f);
        C[r_g*N + c] = v;
      }
    }
  }
}

// ---------------- 128x64 f32 GEMM (separator) -------
__global__ __launch_bounds__(256) void gemm2(
    const float* __restrict__ A, const float* __restrict__ Bm,
    const float* __restrict__ bias, float* __restrict__ C,
    int M, int N, int K, int lda)
{
  __shared__ float As[16][132];
  __shared__ float Bs[16][68];
  const int tid = threadIdx.x;
  const int tx = tid & 15, ty = tid >> 4;
  const int row0 = blockIdx.y * 128, col0 = blockIdx.x * 64;
  const int am  = tid >> 2;
  const int akg = (tid & 3) * 4;
  const int bk  = tid >> 4, bn = (tid & 15) * 4;

  const float* aptr[2]; bool aok[2];
  #pragma unroll
  for (int i = 0; i < 2; i++){
    int r_l = row0 + am + 64*i;
    aok[i] = (r_l < M);
    aptr[i] = A + (size_t)(aok[i] ? r_l : 0) * lda;
  }
  const bool bfull = (col0 + 64 <= N);

  float acc[8][4] = {};
  const int ksteps = (K + 15) >> 4;
  for (int ks = 0; ks < ksteps; ks++){
    const int k0 = ks << 4;
    #pragma unroll
    for (int i = 0; i < 2; i++){
      float4 v = make_float4(0.f, 0.f, 0.f, 0.f);
      if (aok[i]) v = *(const float4*)(aptr[i] + k0 + akg);
      #pragma unroll
      for (int j = 0; j < 4; j++) As[akg+j][am + 64*i] = ((float*)&v)[j];
    }
    {
      float4 v = make_float4(0.f, 0.f, 0.f, 0.f);
      float* pv = (float*)&v;
      int k = k0 + bk;
      if (k < K){
        if (bfull) v = *(const float4*)(Bm + (size_t)k*N + col0 + bn);
        else {
          #pragma unroll
          for (int j = 0; j < 4; j++){ int c = col0+bn+j; if (c < N) pv[j] = Bm[(size_t)k*N + c]; }
        }
      }
      *(float4*)&Bs[bk][bn] = v;
    }
    __syncthreads();
    #pragma unroll
    for (int kk = 0; kk < 16; kk++){
      float av[8], bv[4];
      #pragma unroll
      for (int i = 0; i < 8; i++) av[i] = As[kk][ty*8+i];
      #pragma unroll
      for (int j = 0; j < 4; j++) bv[j] = Bs[kk][tx*4+j];
      #pragma unroll
      for (int i = 0; i < 8; i++)
        #pragma unroll
        for (int j = 0; j < 4; j++) acc[i][j] = fmaf(av[i], bv[j], acc[i][j]);
    }
    __syncthreads();
  }
  float bb[4];
  #pragma unroll
  for (int j = 0; j < 4; j++){
    int c = col0 + tx*4 + j;
    bb[j] = (bias && c < N) ? bias[c] : 0.f;
  }
  #pragma unroll
  for (int i = 0; i < 8; i++){
    int r_l = row0 + ty*8 + i;
    if (r_l >= M) continue;
    size_t r_g = (size_t)r_l;
    int c0 = col0 + tx*4;
    if (bfull){
      float4 o; float* po = (float*)&o;
      #pragma unroll
      for (int j = 0; j < 4; j++) po[j] = acc[i][j] + bb[j];
      *(float4*)(C + r_g*N + c0) = o;
    } else {
      #pragma unroll
      for (int j = 0; j < 4; j++){
        int c = c0 + j;
        if (c >= N) continue;
        C[r_g*N + c] = acc[i][j] + bb[j];
      }
    }
  }
}

// ================= fused MFMA TCN: 2 kernels/layer =================
// k_ka: x_new = xr + rstd2*U + cadd (prev layer, deferred); y = PReLU(x_new@W1+b1);
//       stats1 -> gs; nb==0 writes x_new f32 to xw.
__global__ __launch_bounds__(256) void k_ka(
    const float* __restrict__ xr, float* __restrict__ xw,
    const float* __restrict__ U, const float* __restrict__ gsPrev,
    const float* __restrict__ c2bPrev, const float* __restrict__ ccPrev,
    const ushort* __restrict__ w1p, const float* __restrict__ bias,
    const float* __restrict__ pa, ushort* __restrict__ yb,
    float* __restrict__ gs, int hasU)
{
  __shared__ float red[8];
  int tid = threadIdx.x;
  int wv = tid >> 6, l = tid & 63;
  int b = blockIdx.z, mt = blockIdx.y, nb = blockIdx.x;
  int row0 = mt*64 + wv*16;
  int lm = l & 15, lq = l >> 4;
  int row = row0 + lm;
  bool rok = row < T_;
  size_t rbase = ((size_t)b*T_ + row)*256;
  float rstd2 = 0.f, mr = 0.f;
  if (hasU){
    const float icnt = 1.f/((float)T_*(float)H_);
    float m2 = gsPrev[b*2]*icnt;
    rstd2 = rsqrtf(gsPrev[b*2+1]*icnt - m2*m2 + MEPS);
    mr = m2*rstd2;
  }
  int n0 = nb*64;
  f32x4 acc[4] = {};
  #pragma unroll
  for (int kc = 0; kc < 8; kc++){
    int k0 = kc*32 + lq*8;
    float xv[8];
    *(float4*)&xv[0] = *(const float4*)(xr + rbase + k0);
    *(float4*)&xv[4] = *(const float4*)(xr + rbase + k0 + 4);
    if (hasU){
      float uv[8], cb[8], c1v[8], c2v[8];
      *(float4*)&uv[0]  = *(const float4*)(U + rbase + k0);
      *(float4*)&uv[4]  = *(const float4*)(U + rbase + k0 + 4);
      *(float4*)&cb[0]  = *(const float4*)(c2bPrev + k0);
      *(float4*)&cb[4]  = *(const float4*)(c2bPrev + k0 + 4);
      *(float4*)&c1v[0] = *(const float4*)(ccPrev + k0);
      *(float4*)&c1v[4] = *(const float4*)(ccPrev + k0 + 4);
      *(float4*)&c2v[0] = *(const float4*)(ccPrev + 256 + k0);
      *(float4*)&c2v[4] = *(const float4*)(ccPrev + 256 + k0 + 4);
      #pragma unroll
      for (int j = 0; j < 8; j++)
        xv[j] = xv[j] + rstd2*uv[j] + cb[j] + c1v[j] - mr*c2v[j];
      if (nb == 0 && rok){
        *(float4*)(xw + rbase + k0)     = *(float4*)&xv[0];
        *(float4*)(xw + rbase + k0 + 4) = *(float4*)&xv[4];
      }
    }
    bf16x8 a;
    #pragma unroll
    for (int j = 0; j < 8; j++) a[j] = (short)f2bf(xv[j]);
    #pragma unroll
    for (int nt = 0; nt < 4; nt++){
      bf16x8 bf = *(const bf16x8*)(w1p + (((size_t)kc*32 + (n0>>4) + nt)*64 + l)*8);
      acc[nt] = __builtin_amdgcn_mfma_f32_16x16x32_bf16(a, bf, acc[nt], 0, 0, 0);
    }
  }
  float ps = 0.f, pss = 0.f;
  #pragma unroll
  for (int nt = 0; nt < 4; nt++){
    int col = n0 + nt*16 + lm;
    float bb = bias[col], pav = pa[col];
    #pragma unroll
    for (int r = 0; r < 4; r++){
      int t = row0 + lq*4 + r;
      if (t < T_){
        float v = acc[nt][r] + bb;
        float p = fmaxf(v, 0.f) + pav*fminf(v, 0.f);
        yb[((size_t)b*T_ + t)*512 + col] = f2bf(p);
        ps += p; pss += p*p;
      }
    }
  }
  #pragma unroll
  for (int off = 32; off > 0; off >>= 1){
    ps  += __shfl_down(ps, off);
    pss += __shfl_down(pss, off);
  }
  if (l == 0){ red[wv*2] = ps; red[wv*2+1] = pss; }
  __syncthreads();
  if (tid == 0) atomicAdd(&gs[b*2],   red[0]+red[2]+red[4]+red[6]);
  if (tid == 1) atomicAdd(&gs[b*2+1], red[1]+red[3]+red[5]+red[7]);
}

// k_kb: recompute p2 = PReLU2(dwconv(gLN1affine(y))) inline per A-fragment;
//       U = p2 @ (g2 (.) W2); nb==0 accumulates stats2(p2) -> gs2.
__global__ __launch_bounds__(256) void k_kb(
    const ushort* __restrict__ yb, const ushort* __restrict__ w2p,
    const float* __restrict__ dwk, const float* __restrict__ gg,
    const float* __restrict__ gb, const float* __restrict__ gs1,
    const float* __restrict__ pa, float* __restrict__ U,
    float* __restrict__ gs2, int dil)
{
  __shared__ float red[8];
  int tid = threadIdx.x;
  int wv = tid >> 6, l = tid & 63;
  int b = blockIdx.z, mt = blockIdx.y, nb = blockIdx.x;
  int row0 = mt*64 + wv*16;
  int lm = l & 15, lq = l >> 4;
  int t = row0 + lm;
  bool rok = t < T_;
  const float icnt = 1.f/((float)T_*(float)H_);
  float m1 = gs1[b*2]*icnt;
  float rstd1 = rsqrtf(gs1[b*2+1]*icnt - m1*m1 + MEPS);
  int n0 = nb*32;
  f32x4 acc[2] = {};
  float sp = 0.f, spp = 0.f;
  const bool dostat = (nb == 0) && rok;
  #pragma unroll
  for (int kc = 0; kc < 16; kc++){
    int ch0 = kc*32 + lq*8;
    float ga[8], ba[8];
    {
      float g8[8], b8[8];
      *(float4*)&g8[0] = *(const float4*)(gg + ch0);
      *(float4*)&g8[4] = *(const float4*)(gg + ch0 + 4);
      *(float4*)&b8[0] = *(const float4*)(gb + ch0);
      *(float4*)&b8[4] = *(const float4*)(gb + ch0 + 4);
      #pragma unroll
      for (int j = 0; j < 8; j++){ ga[j] = g8[j]*rstd1; ba[j] = b8[j] - m1*ga[j]; }
    }
    float z[8] = {0.f,0.f,0.f,0.f,0.f,0.f,0.f,0.f};
    #pragma unroll
    for (int kk = 0; kk < 3; kk++){
      int tt = t + (kk-1)*dil;
      if (tt >= 0 && tt < T_){
        bf16x8 yv = *(const bf16x8*)(yb + ((size_t)b*T_ + tt)*512 + ch0);
        float d8[8];
        *(float4*)&d8[0] = *(const float4*)(dwk + kk*H_ + ch0);
        *(float4*)&d8[4] = *(const float4*)(dwk + kk*H_ + ch0 + 4);
        #pragma unroll
        for (int j = 0; j < 8; j++)
          z[j] = fmaf(d8[j], bf2f((ushort)yv[j])*ga[j] + ba[j], z[j]);
      }
    }
    float pa8[8];
    *(float4*)&pa8[0] = *(const float4*)(pa + ch0);
    *(float4*)&pa8[4] = *(const float4*)(pa + ch0 + 4);
    bf16x8 a;
    #pragma unroll
    for (int j = 0; j < 8; j++){
      float p = fmaxf(z[j], 0.f) + pa8[j]*fminf(z[j], 0.f);
      if (dostat){ sp += p; spp += p*p; }
      a[j] = (short)f2bf(p);
    }
    #pragma unroll
    for (int nt = 0; nt < 2; nt++){
      bf16x8 bf = *(const bf16x8*)(w2p + (((size_t)kc*16 + (n0>>4) + nt)*64 + l)*8);
      acc[nt] = __builtin_amdgcn_mfma_f32_16x16x32_bf16(a, bf, acc[nt], 0, 0, 0);
    }
  }
  #pragma unroll
  for (int nt = 0; nt < 2; nt++){
    int col = n0 + nt*16 + lm;
    #pragma unroll
    for (int r = 0; r < 4; r++){
      int tr = row0 + lq*4 + r;
      if (tr < T_) U[((size_t)b*T_ + tr)*256 + col] = acc[nt][r];
    }
  }
  if (nb == 0){
    #pragma unroll
    for (int off = 32; off > 0; off >>= 1){
      sp  += __shfl_down(sp, off);
      spp += __shfl_down(spp, off);
    }
    if (l == 0){ red[wv*2] = sp; red[wv*2+1] = spp; }
    __syncthreads();
    if (tid == 0) atomicAdd(&gs2[b*2],   red[0]+red[2]+red[4]+red[6]);
    if (tid == 1) atomicAdd(&gs2[b*2+1], red[1]+red[3]+red[5]+red[7]);
  }
}

// final deferred apply after layer 31
__global__ __launch_bounds__(256) void k_applyx(
    const float* __restrict__ xr, const float* __restrict__ U,
    const float* __restrict__ gs, const float* __restrict__ c2b,
    const float* __restrict__ cc, float* __restrict__ xo)
{
  int i = blockIdx.x*256 + threadIdx.x;
  if (i < B_*T_*256){
    int b = i / (T_*256);
    int k = i & 255;
    const float icnt = 1.f/((float)T_*(float)H_);
    float m = gs[b*2]*icnt;
    float rstd = rsqrtf(gs[b*2+1]*icnt - m*m + MEPS);
    float mr = m*rstd;
    xo[i] = xr[i] + rstd*U[i] + c2b[k] + cc[k] - mr*cc[256 + k];
  }
}

// ---------------- cLN over [enc | log1p(mag)] ----------------
__global__ __launch_bounds__(256) void k_cln(
    const float* __restrict__ cf,
    const float* __restrict__ gamma, const float* __restrict__ beta,
    float* __restrict__ mag, float* __restrict__ cosp, float* __restrict__ sinp,
    float* __restrict__ xln){
  int t = blockIdx.x, b = blockIdx.y, tid = threadIdx.x;
  size_t row = (size_t)b*T_ + t;
  __shared__ float feat[FC];
  __shared__ float red[8];
  feat[tid] = cf[row*FRSTR + tid];
  if (tid < NFREQ){
    float re = cf[row*FRSTR + 256 + tid], im = cf[row*FRSTR + 385 + tid];
    float m = sqrtf(re*re + im*im);
    mag[row*NFREQ + tid] = m;
    float c = 1.f, s = 0.f;
    if (m > 0.f){ c = re/m; s = im/m; }
    cosp[row*NFREQ + tid] = c;
    sinp[row*NFREQ + tid] = s;
    feat[AE + tid] = log1pf(m);
  }
  __syncthreads();
  float v = feat[tid] + ((tid < FC-256) ? feat[256+tid] : 0.f);
  #pragma unroll
  for (int off = 32; off > 0; off >>= 1) v += __shfl_down(v, off);
  if ((tid & 63) == 0) red[tid>>6] = v;
  __syncthreads();
  float mean = (red[0]+red[1]+red[2]+red[3]) * (1.0f/FC);
  float d0 = feat[tid] - mean;
  float vv = d0*d0;
  if (tid < FC-256){ float d1 = feat[256+tid] - mean; vv += d1*d1; }
  __syncthreads();
  #pragma unroll
  for (int off = 32; off > 0; off >>= 1) vv += __shfl_down(vv, off);
  if ((tid & 63) == 0) red[tid>>6] = vv;
  __syncthreads();
  float var = (red[0]+red[1]+red[2]+red[3]) * (1.0f/FC);
  float rstd = rsqrtf(var + MEPS);
  xln[row*XSTR + tid] = (feat[tid]-mean)*rstd*gamma[tid] + beta[tid];
  if (tid < FC-256)
    xln[row*XSTR + 256+tid] = (feat[256+tid]-mean)*rstd*gamma[256+tid] + beta[256+tid];
  if (tid < XSTR-FC) xln[row*XSTR + FC + tid] = 0.f;
}

// ---------------- attractor accumulation ------------
#define ATTR_CH 16
__global__ __launch_bounds__(256) void k_attr2(const float* __restrict__ emb,
                                               const float* __restrict__ anchors,
                                               float* __restrict__ acc){
  const int c0a[16] = {0,0,0,0,0,1,1,1,1,2,2,2,3,3,4,0};
  const int c1a[16] = {1,2,3,4,5,2,3,4,5,3,4,5,4,5,5,0};
  int by = blockIdx.y;
  int b = by >> 2, g = by & 3;
  int tid = threadIdx.x;
  __shared__ float anc[6][20];
  __shared__ float wred[4][84];
  if (tid < 120) anc[tid/20][tid%20] = anchors[tid];
  __syncthreads();
  float ar[4][21];
  #pragma unroll
  for (int q = 0; q < 4; q++)
    #pragma unroll
    for (int e = 0; e < 21; e++) ar[q][e] = 0.f;
  const float* eb = emb + (size_t)b*KB*EMBED;
  for (int k = blockIdx.x*256 + tid; k < KB; k += ATTR_CH*256){
    float e[20];
    const float4* p = (const float4*)(eb + (size_t)k*EMBED);
    #pragma unroll
    for (int i = 0; i < 5; i++){
      float4 v = p[i];
      e[4*i] = v.x; e[4*i+1] = v.y; e[4*i+2] = v.z; e[4*i+3] = v.w;
    }
    float d[6];
    #pragma unroll
    for (int c = 0; c < 6; c++){
      float s = 0.f;
      #pragma unroll
      for (int j = 0; j < 20; j++) s = fmaf(e[j], anc[c][j], s);
      d[c] = s;
    }
    #pragma unroll
    for (int q = 0; q < 4; q++){
      int s = g*4 + q;
      float w = (s == 15) ? 1.0f : 1.0f / (1.0f + expf(d[c1a[s]] - d[c0a[s]]));
      #pragma unroll
      for (int j = 0; j < 20; j++) ar[q][j] = fmaf(w, e[j], ar[q][j]);
      ar[q][20] += w;
    }
  }
  #pragma unroll
  for (int q = 0; q < 4; q++)
    #pragma unroll
    for (int e = 0; e < 21; e++)
      #pragma unroll
      for (int off = 32; off > 0; off >>= 1)
        ar[q][e] += __shfl_down(ar[q][e], off);
  if ((tid & 63) == 0){
    int w = tid >> 6;
    #pragma unroll
    for (int q = 0; q < 4; q++)
      #pragma unroll
      for (int e = 0; e < 21; e++) wred[w][q*21+e] = ar[q][e];
  }
  __syncthreads();
  if (tid < 84){
    float s = wred[0][tid] + wred[1][tid] + wred[2][tid] + wred[3][tid];
    int q = tid / 21, e = tid % 21;
    atomicAdd(&acc[((size_t)b*16 + g*4 + q)*21 + e], s);
  }
}

// ---------------- attractor normalize + select ----------------
__global__ __launch_bounds__(128) void k_attrfin2(const float* __restrict__ acc,
                                                  float* __restrict__ attractors){
  __shared__ float aN[120][40];
  __shared__ float sp[120];
  int tid = threadIdx.x;
  if (tid < 120){
    int b = tid / 15, p = tid % 15;
    const float* ap = acc + ((size_t)b*16 + p)*21;
    const float* ae = acc + ((size_t)b*16 + 15)*21;
    float den0 = ap[20];
    float den1 = (float)KB - den0;
    float s = 0.f;
    for (int e = 0; e < 20; e++){
      float a0 = ap[e] / den0;
      float a1 = (ae[e] - ap[e]) / den1;
      aN[tid][e] = a0; aN[tid][20+e] = a1;
      s = fmaf(a0, a1, s);
    }
    sp[tid] = s;
  }
  __syncthreads();
  if (tid < B_){
    int base = tid * 15, best = 0;
    float bv = sp[base];
    for (int p = 1; p < 15; p++) if (sp[base+p] < bv){ bv = sp[base+p]; best = p; }
    for (int i = 0; i < 40; i++) attractors[tid*40 + i] = aN[base+best][i];
  }
}

// ---------------- build decoder-GEMM A rows (stride 516, pads zeroed) -------
__global__ __launch_bounds__(256) void k_afull(
    const float* __restrict__ emb, const float* __restrict__ cf,
    const float* __restrict__ mag, const float* __restrict__ cosp,
    const float* __restrict__ sinp, const float* __restrict__ attractors,
    float* __restrict__ Af){
  int t = blockIdx.x, b = blockIdx.y, tid = threadIdx.x;
  __shared__ float att[40];
  if (tid < 40) att[tid] = attractors[b*40 + tid];
  __syncthreads();
  size_t row = (size_t)b*T_ + t;
  size_t r0 = ((size_t)(b*2+0)*T_ + t)*AFSTR;
  size_t r1 = ((size_t)(b*2+1)*T_ + t)*AFSTR;
  for (int f = tid; f < FC; f += 256){
    const float* e = emb + (row*FC + f)*20;
    float l0 = 0.f, l1 = 0.f;
    #pragma unroll
    for (int j = 0; j < 20; j++){
      float ev = e[j];
      l0 = fmaf(ev, att[j],    l0);
      l1 = fmaf(ev, att[20+j], l1);
    }
    if (f < AE){
      float ft = cf[row*FRSTR + f];
      Af[r0 + f] = l0*ft;
      Af[r1 + f] = l1*ft;
    } else {
      int fi = f - AE;
      float ft = mag[row*NFREQ + fi];
      float c = cosp[row*NFREQ + fi], s = sinp[row*NFREQ + fi];
      float s0 = l0*ft, s1v = l1*ft;
      Af[r0 + 256 + fi] = c*s0;  Af[r0 + 385 + fi] = s*s0;
      Af[r1 + 256 + fi] = c*s1v; Af[r1 + 385 + fi] = s*s1v;
    }
  }
  if (tid < 2){
    Af[r0 + 514 + tid] = 0.f;
    Af[r1 + 514 + tid] = 0.f;
  }
}

// ---------------- overlap-add gather ----------------
__global__ __launch_bounds__(256) void k_ola(const float* __restrict__ frames,
                                             float* __restrict__ out){
  int i = blockIdx.x*256 + threadIdx.x;
  if (i < B_*2*L_){
    int bs = i / L_, l = i % L_;
    int t0 = l >> 6;
    float s = 0.f;
    #pragma unroll
    for (int j = 0; j < 4; j++){
      int t = t0 - j;
      if (t >= 0 && t < T_){
        int k = l - t*64;
        s += frames[((size_t)bs*T_ + t)*256 + k];
      }
    }
    out[i] = s;
  }
}

// ---------------- launcher ----------------
extern "C" void kernel_launch(void* const* d_in, const int* in_sizes, int n_in,
                              void* d_out, int out_size, void* d_ws, size_t ws_size,
                              hipStream_t stream) {
  const float* audios   = (const float*)d_in[0];
  const float* enc_w    = (const float*)d_in[1];
  const float* enc_b    = (const float*)d_in[2];
  const float* bgamma   = (const float*)d_in[3];
  const float* bbeta    = (const float*)d_in[4];
  const float* bottle_w = (const float*)d_in[5];
  const float* bottle_b = (const float*)d_in[6];
  const float* c1_w     = (const float*)d_in[7];
  const float* c1_b     = (const float*)d_in[8];
  const float* p1       = (const float*)d_in[9];
  const float* g1_g     = (const float*)d_in[10];
  const float* g1_b     = (const float*)d_in[11];
  const float* dwp      = (const float*)d_in[12];
  const float* p2       = (const float*)d_in[13];
  const float* g2_g     = (const float*)d_in[14];
  const float* g2_b     = (const float*)d_in[15];
  const float* c2_w     = (const float*)d_in[16];
  const float* c2_b     = (const float*)d_in[17];
  const float* sep_w    = (const float*)d_in[18];
  const float* sep_b    = (const float*)d_in[19];
  const float* anchors  = (const float*)d_in[20];
  const float* dec_w    = (const float*)d_in[21];
  const float* dec_b    = (const float*)d_in[22];

  float* ws = (float*)d_ws;
  float* bfr   = ws + o_bfr;
  float* decB  = ws + o_decB;
  float* decBias = ws + o_decBias;
  float* biasF = ws + o_biasF;
  float* cf    = ws + o_cf;
  float* mag   = ws + o_mag;
  float* cosp  = ws + o_cosp;
  float* sinp  = ws + o_sinp;
  float* xln   = ws + o_xln;
  float* xbuf0 = ws + o_x;
  float* xbuf1 = ws + o_y;                         // first half of o_y region
  float* Ubuf  = ws + o_y + (size_t)B_*T_*BTL;     // second half
  float* gsum  = ws + o_gsum;
  float* accp  = ws + o_acc;
  float* attp  = ws + o_att;
  float* embp  = ws + o_emb;
  float* Afull = ws + o_Af;
  float* framesp = ws + o_fr;
  float* c1c2  = ws + o_c1c2;
  ushort* w1p  = (ushort*)(ws + o_w1p);
  ushort* w2p  = (ushort*)(ws + o_w2p);
  ushort* yb16 = (ushort*)(ws + o_z);

  // zero atomic accumulators (gsum 1024 + attr acc 2688, contiguous)
  hipMemsetAsync((void*)gsum, 0, (1024 + (size_t)B_*16*21) * sizeof(float), stream);

  k_prep<<<(256*516 + 514*256 + 256 + 516 + 255)/256, 256, 0, stream>>>(
      enc_w, enc_b, dec_w, dec_b, bfr, decB, decBias, biasF);
  k_packw<<<(int)((2u*32u*131072u + 255)/256), 256, 0, stream>>>(
      c1_w, c2_w, g2_g, w1p, w2p);
  k_bias2<<<32, 256, 0, stream>>>(c2_w, g2_g, g2_b, c1c2);

  // frames GEMM: mix-on-load, [enc | spec] out, M=3976, N=516, K=256
  gemm3<2><<<dim3(9, 63), 256, 0, stream>>>(
      audios, bfr, biasF, cf, B_*T_, FRSTR, 256, 0, FRSTR, 256);

  k_cln<<<dim3(T_, B_), 256, 0, stream>>>(cf, bgamma, bbeta, mag, cosp, sinp, xln);

  // bottleneck -> x(0) in buf0
  gemm3<0><<<dim3(4, 63), 256, 0, stream>>>(
      xln, bottle_w, bottle_b, xbuf0, B_*T_, BTL, FC, XSTR, BTL, 0);

  // TCN: 2 kernels per layer; deferred c2-apply folded into next layer's A-load
  float* bufs[2] = { xbuf0, xbuf1 };
  for (int i = 0; i < NB; i++){
    int dil = 1 << (i & 7);
    const float* xr = (i == 0) ? xbuf0 : bufs[(i-1) & 1];
    float* xw = bufs[i & 1];
    const float* gsPrev = (i == 0) ? gsum : (gsum + (i-1)*32 + 16);
    const float* c2bPrev = c2_b + (size_t)((i > 0) ? (i-1) : 0)*BTL;
    const float* ccPrev  = c1c2 + (size_t)((i > 0) ? (i-1) : 0)*512;
    k_ka<<<dim3(8, 8, B_), 256, 0, stream>>>(
        xr, xw, Ubuf, gsPrev, c2bPrev, ccPrev,
        w1p + (size_t)i*131072, c1_b + i*H_, p1 + i*H_,
        yb16, gsum + i*32, (i > 0) ? 1 : 0);
    k_kb<<<dim3(8, 8, B_), 256, 0, stream>>>(
        yb16, w2p + (size_t)i*131072, dwp + (size_t)i*3*H_,
        g1_g + i*H_, g1_b + i*H_, gsum + i*32, p2 + i*H_,
        Ubuf, gsum + i*32 + 16, dil);
  }
  // final apply: x_final = x(31) + rstd2*U(31) + cadd(31) -> buf0 (x(31) is in buf1)
  k_applyx<<<(B_*T_*256 + 255)/256, 256, 0, stream>>>(
      bufs[(NB-1) & 1], Ubuf, gsum + (NB-1)*32 + 16,
      c2_b + (size_t)(NB-1)*BTL, c1c2 + (size_t)(NB-1)*512, xbuf0);

  // separator: M=3976, N=7700, K=256
  gemm2<<<dim3(121, 32), 256, 0, stream>>>(
      xbuf0, sep_w, sep_b, embp, B_*T_, FC*EMBED, BTL, BTL);

  // attractors
  k_attr2<<<dim3(ATTR_CH, B_*4), 256, 0, stream>>>(embp, anchors, accp);
  k_attrfin2<<<1, 128, 0, stream>>>(accp, attp);

  // decode: M=7952, N=256, K=514 (lda=516, zero-padded)
  k_afull<<<dim3(T_, B_), 256, 0, stream>>>(embp, cf, mag, cosp, sinp, attp, Afull);
  gemm3<0><<<dim3(4, 125), 256, 0, stream>>>(
      Afull, decB, decBias, framesp, 2*B_*T_, 256, 514, AFSTR, BTL, 0);
  k_ola<<<(B_*2*L_ + 255)/256, 256, 0, stream>>>(framesp, (float*)d_out);
}

// Round 10
// 2513.474 us; speedup vs baseline: 6.2634x; 1.0193x over previous
//
#include <hip/hip_runtime.h>
#include <math.h>

#define B_ 8
#define S_ 2
#define L_ 32000
#define T_ 497
#define AE 256
#define NFREQ 129
#define FC 385
#define XSTR 388
#define FRSTR 516
#define AFSTR 516
#define BTL 256
#define H_ 512
#define NB 32
#define EMBED 20
#define KB (T_*FC)
#define MEPS 1e-12f
#define PI2F 6.28318530717958647692f

typedef __attribute__((ext_vector_type(8))) short bf16x8;
typedef __attribute__((ext_vector_type(4))) float f32x4;

__device__ __forceinline__ ushort f2bf(float f){
  union { float f; unsigned u; } x; x.f = f;
  unsigned r = x.u + 0x7FFFu + ((x.u >> 16) & 1u);
  return (ushort)(r >> 16);
}
__device__ __forceinline__ float bf2f(ushort h){
  union { unsigned u; float f; } x; x.u = ((unsigned)h) << 16;
  return x.f;
}

// ---------------- workspace layout (float units) ----------------
static constexpr size_t ALGN(size_t x){ return (x + 63) & ~(size_t)63; }
static constexpr size_t o_bfr  = 0;                                   // 256*516
static constexpr size_t o_decB = ALGN(o_bfr + (size_t)256*516);       // 514*256
static constexpr size_t o_decBias = ALGN(o_decB + (size_t)514*256);   // 256
static constexpr size_t o_biasF  = ALGN(o_decBias + 256);             // 516
static constexpr size_t o_cf   = ALGN(o_biasF + 516);                 // 3976*516
static constexpr size_t o_mag  = ALGN(o_cf + (size_t)B_*T_*FRSTR);
static constexpr size_t o_cosp = ALGN(o_mag + (size_t)B_*T_*NFREQ);
static constexpr size_t o_sinp = ALGN(o_cosp + (size_t)B_*T_*NFREQ);
static constexpr size_t o_xln  = ALGN(o_sinp + (size_t)B_*T_*NFREQ);
static constexpr size_t o_x    = ALGN(o_xln + (size_t)B_*T_*XSTR);   // x buf0 (3976*256)
static constexpr size_t o_y    = ALGN(o_x + (size_t)B_*T_*BTL);      // x buf1 + U  (2*3976*256) ; later framesp
static constexpr size_t o_z    = ALGN(o_y + (size_t)B_*T_*H_);       // yb16 (bf16 3976*512 + pad)
static constexpr size_t o_gsum = ALGN(o_z + (size_t)B_*T_*H_);       // 32*32
static constexpr size_t o_acc  = o_gsum + 1024;                      // B*16*21
static constexpr size_t o_att  = ALGN(o_acc + (size_t)B_*16*21);
static constexpr size_t o_emb  = ALGN(o_att + (size_t)B_*2*EMBED);
static constexpr size_t o_Af   = ALGN(o_emb + (size_t)B_*KB*EMBED);  // 7952*516
static constexpr size_t o_w1p  = ALGN(o_Af + (size_t)2*B_*T_*AFSTR); // 32*131072 ush
static constexpr size_t o_w2p  = ALGN(o_w1p + (size_t)2097152);
static constexpr size_t o_c1c2 = ALGN(o_w2p + (size_t)2097152);      // 32*512
static constexpr size_t o_fr   = o_y;

#define PREP_BLOCKS 1034
#define PACKW_BLOCKS 32768
#define BIAS2_BLOCKS 256

// ---------------- merged setup: bases/biases + weight packing + bias2 fold ---
__global__ __launch_bounds__(256) void k_setup(
    const float* __restrict__ enc_w, const float* __restrict__ enc_b,
    const float* __restrict__ dec_w, const float* __restrict__ dec_b,
    const float* __restrict__ c1_w, const float* __restrict__ c2_w,
    const float* __restrict__ g2_g, const float* __restrict__ g2_b,
    float* __restrict__ bfr, float* __restrict__ decB,
    float* __restrict__ decBias, float* __restrict__ biasF,
    ushort* __restrict__ w1p, ushort* __restrict__ w2p,
    float* __restrict__ c1c2)
{
  int bx = blockIdx.x;
  if (bx < PREP_BLOCKS){
    int i = bx*256 + threadIdx.x;
    if (i < 256*516){
      int k = i / 516, n = i % 516;
      float v;
      if (n < 256) v = enc_w[(size_t)k*256 + n];
      else if (n < 514){
        int f2 = n - 256;
        float win = sqrtf(0.5f - 0.5f*cosf(PI2F * (float)k / 256.0f));
        int f = (f2 < NFREQ) ? f2 : (f2 - NFREQ);
        int m = (k * f) & 255;
        float th = PI2F * (float)m / 256.0f;
        v = (f2 < NFREQ) ? win * cosf(th) : -win * sinf(th);
      } else v = 0.f;
      bfr[i] = v;
      return;
    }
    int j = i - 256*516;
    if (j < 514*256){
      int k = j / 256, n = j & 255;
      float v;
      if (k < 256){
        v = 0.5f * dec_w[(size_t)k*256 + n];
      } else {
        int m = n & 63;
        float den = 0.f;
        #pragma unroll
        for (int q = 0; q < 4; q++) den += 0.5f - 0.5f*cosf(PI2F*(float)(m + 64*q)/256.0f);
        float win = sqrtf(0.5f - 0.5f*cosf(PI2F*(float)n/256.0f));
        float iw = win / den;
        int f = (k < 385) ? (k - 256) : (k - 385);
        int mm = (f * n) & 255;
        float th = PI2F * (float)mm / 256.0f;
        if (k < 385){
          float cf = (f==0 || f==128) ? 1.0f : 2.0f;
          v = 0.5f * iw * cf * cosf(th) * (1.0f/256.0f);
        } else {
          v = (f==0 || f==128) ? 0.0f : -1.0f * iw * sinf(th) * (1.0f/256.0f);
        }
      }
      decB[j] = v;
      return;
    }
    int jj = j - 514*256;
    if (jj < 256){ decBias[jj] = 0.5f * dec_b[jj]; return; }
    int n = jj - 256;
    if (n < 516) biasF[n] = (n < 256) ? enc_b[n] : 0.f;
    return;
  }
  if (bx < PREP_BLOCKS + PACKW_BLOCKS){
    size_t idx = (size_t)(bx - PREP_BLOCKS)*256 + threadIdx.x;
    const size_t PER = (size_t)32*131072;
    if (idx < PER){
      int i = (int)(idx >> 17);
      int o = (int)(idx & 131071);
      int kc = o >> 14;
      int n16 = (o >> 9) & 31;
      int l = (o >> 3) & 63;
      int j = o & 7;
      int k = kc*32 + (l>>4)*8 + j;
      int n = n16*16 + (l&15);
      w1p[idx] = f2bf(c1_w[((size_t)i*256 + k)*512 + n]);
    } else {
      size_t o2 = idx - PER;
      int i = (int)(o2 >> 17);
      int o = (int)(o2 & 131071);
      int kc = o >> 13;
      int n16 = (o >> 9) & 15;
      int l = (o >> 3) & 63;
      int j = o & 7;
      int k = kc*32 + (l>>4)*8 + j;
      int n = n16*16 + (l&15);
      w2p[o2] = f2bf(g2_g[(size_t)i*512 + k] * c2_w[((size_t)i*512 + k)*256 + n]);
    }
    return;
  }
  // bias2 fold: block (layer i, k-slab ks); 8-way atomic accumulation
  int bi = bx - (PREP_BLOCKS + PACKW_BLOCKS);
  int i = bi >> 3, ks = bi & 7;
  int n = threadIdx.x;
  float s1 = 0.f, s2 = 0.f;
  for (int k = ks*64; k < ks*64 + 64; k++){
    float w = c2_w[((size_t)i*512 + k)*256 + n];
    s1 = fmaf(g2_b[(size_t)i*512 + k], w, s1);
    s2 = fmaf(g2_g[(size_t)i*512 + k], w, s2);
  }
  atomicAdd(&c1c2[(size_t)i*512 + n], s1);
  atomicAdd(&c1c2[(size_t)i*512 + 256 + n], s2);
}

// ---------------- pipelined 64x64 GEMM (non-TCN) ----------------
template<int ALOAD>
__global__ __launch_bounds__(256, 2) void gemm3(
    const float* __restrict__ A, const float* __restrict__ Bm,
    const float* __restrict__ bias, float* __restrict__ C,
    int M, int N, int K, int lda, int ldb, int relu_cols)
{
  __shared__ float As[16][68];
  __shared__ float Bs[16][68];
  const int tid = threadIdx.x;
  const int tx = tid & 15, ty = tid >> 4;
  const int row0 = blockIdx.y*64, col0 = blockIdx.x*64;
  const int am = tid >> 2, ak = (tid & 3)*4;
  const int bk = tid >> 4, bn = (tid & 15)*4;
  const int arow = row0 + am;
  const bool aok = arow < M;
  const float* aptr = nullptr;
  const float* ap0 = nullptr; const float* ap1 = nullptr;
  if (ALOAD == 2){
    int r = aok ? arow : 0;
    int b = r / T_, t = r % T_;
    ap0 = A + ((size_t)b*2)*L_ + t*64;
    ap1 = ap0 + L_;
  } else {
    aptr = A + (size_t)(aok ? arow : 0)*lda;
  }
  const bool bfull = (col0 + 64 <= N);
  const int ksteps = (K+15) >> 4;

  float4 av, bv;

#define LOADA(ks_) { int k0 = (ks_) << 4; \
    av = make_float4(0.f,0.f,0.f,0.f); \
    if (aok){ \
      if (ALOAD == 2){ \
        float4 u = *(const float4*)(ap0 + k0 + ak); \
        float4 w = *(const float4*)(ap1 + k0 + ak); \
        av.x = u.x+w.x; av.y = u.y+w.y; av.z = u.z+w.z; av.w = u.w+w.w; \
      } else if (k0 + ak + 4 <= lda){ \
        av = *(const float4*)(aptr + k0 + ak); \
      } else { \
        float* pv = (float*)&av; \
        for (int j = 0; j < 4; j++){ int k = k0+ak+j; if (k < K) pv[j] = aptr[k]; } \
      } \
    } }

#define LOADB(ks_) { int k = ((ks_) << 4) + bk; \
    bv = make_float4(0.f,0.f,0.f,0.f); \
    if (k < K){ \
      if (bfull) bv = *(const float4*)(Bm + (size_t)k*ldb + col0 + bn); \
      else { float* pv = (float*)&bv; \
        for (int j = 0; j < 4; j++){ int c = col0+bn+j; if (c < N) pv[j] = Bm[(size_t)k*ldb + c]; } } } }

  float acc[4][4] = {};
  LOADA(0); LOADB(0);
  for (int ks = 0; ks < ksteps; ks++){
    As[ak+0][am] = av.x; As[ak+1][am] = av.y;
    As[ak+2][am] = av.z; As[ak+3][am] = av.w;
    *(float4*)&Bs[bk][bn] = bv;
    __syncthreads();
    if (ks + 1 < ksteps){ LOADA(ks+1); LOADB(ks+1); }
    #pragma unroll
    for (int kk = 0; kk < 16; kk++){
      float a4[4], b4[4];
      *(float4*)a4 = *(const float4*)&As[kk][ty*4];
      *(float4*)b4 = *(const float4*)&Bs[kk][tx*4];
      #pragma unroll
      for (int i = 0; i < 4; i++)
        #pragma unroll
        for (int j = 0; j < 4; j++) acc[i][j] = fmaf(a4[i], b4[j], acc[i][j]);
    }
    __syncthreads();
  }
#undef LOADA
#undef LOADB

  float bb4[4];
  #pragma unroll
  for (int j = 0; j < 4; j++){
    int c = col0 + tx*4 + j;
    bb4[j] = (bias && c < N) ? bias[c] : 0.f;
  }
  #pragma unroll
  for (int i = 0; i < 4; i++){
    int r_l = row0 + ty*4 + i;
    if (r_l >= M) continue;
    size_t r_g = (size_t)r_l;
    int c0 = col0 + tx*4;
    if (bfull){
      float4 o; float* po = (float*)&o;
      #pragma unroll
      for (int j = 0; j < 4; j++){
        float v = acc[i][j] + bb4[j];
        if (c0 + j < relu_cols) v = fmaxf(v, 0.f);
        po[j] = v;
      }
      *(float4*)(C + r_g*N + c0) = o;
    } else {
      #pragma unroll
      for (int j = 0; j < 4; j++){
        int c = c0 + j;
        if (c >= N) continue;
        float v = acc[i][j] + bb4[j];
        if (c < relu_cols) v = fmaxf(v, 0.f);
        C[r_g*N + c] = v;
      }
    }
  }
}

// ---------------- 128x64 f32 GEMM (separator) -------
__global__ __launch_bounds__(256) void gemm2(
    const float* __restrict__ A, const float* __restrict__ Bm,
    const float* __restrict__ bias, float* __restrict__ C,
    int M, int N, int K, int lda)
{
  __shared__ float As[16][132];
  __shared__ float Bs[16][68];
  const int tid = threadIdx.x;
  const int tx = tid & 15, ty = tid >> 4;
  const int row0 = blockIdx.y * 128, col0 = blockIdx.x * 64;
  const int am  = tid >> 2;
  const int akg = (tid & 3) * 4;
  const int bk  = tid >> 4, bn = (tid & 15) * 4;

  const float* aptr[2]; bool aok[2];
  #pragma unroll
  for (int i = 0; i < 2; i++){
    int r_l = row0 + am + 64*i;
    aok[i] = (r_l < M);
    aptr[i] = A + (size_t)(aok[i] ? r_l : 0) * lda;
  }
  const bool bfull = (col0 + 64 <= N);

  float acc[8][4] = {};
  const int ksteps = (K + 15) >> 4;
  for (int ks = 0; ks < ksteps; ks++){
    const int k0 = ks << 4;
    #pragma unroll
    for (int i = 0; i < 2; i++){
      float4 v = make_float4(0.f, 0.f, 0.f, 0.f);
      if (aok[i]) v = *(const float4*)(aptr[i] + k0 + akg);
      #pragma unroll
      for (int j = 0; j < 4; j++) As[akg+j][am + 64*i] = ((float*)&v)[j];
    }
    {
      float4 v = make_float4(0.f, 0.f, 0.f, 0.f);
      float* pv = (float*)&v;
      int k = k0 + bk;
      if (k < K){
        if (bfull) v = *(const float4*)(Bm + (size_t)k*N + col0 + bn);
        else {
          #pragma unroll
          for (int j = 0; j < 4; j++){ int c = col0+bn+j; if (c < N) pv[j] = Bm[(size_t)k*N + c]; }
        }
      }
      *(float4*)&Bs[bk][bn] = v;
    }
    __syncthreads();
    #pragma unroll
    for (int kk = 0; kk < 16; kk++){
      float av[8], bv[4];
      #pragma unroll
      for (int i = 0; i < 8; i++) av[i] = As[kk][ty*8+i];
      #pragma unroll
      for (int j = 0; j < 4; j++) bv[j] = Bs[kk][tx*4+j];
      #pragma unroll
      for (int i = 0; i < 8; i++)
        #pragma unroll
        for (int j = 0; j < 4; j++) acc[i][j] = fmaf(av[i], bv[j], acc[i][j]);
    }
    __syncthreads();
  }
  float bb[4];
  #pragma unroll
  for (int j = 0; j < 4; j++){
    int c = col0 + tx*4 + j;
    bb[j] = (bias && c < N) ? bias[c] : 0.f;
  }
  #pragma unroll
  for (int i = 0; i < 8; i++){
    int r_l = row0 + ty*8 + i;
    if (r_l >= M) continue;
    size_t r_g = (size_t)r_l;
    int c0 = col0 + tx*4;
    if (bfull){
      float4 o; float* po = (float*)&o;
      #pragma unroll
      for (int j = 0; j < 4; j++) po[j] = acc[i][j] + bb[j];
      *(float4*)(C + r_g*N + c0) = o;
    } else {
      #pragma unroll
      for (int j = 0; j < 4; j++){
        int c = c0 + j;
        if (c >= N) continue;
        C[r_g*N + c] = acc[i][j] + bb[j];
      }
    }
  }
}

// ================= fused MFMA TCN: 2 kernels/layer =================
// k_ka: x_new = xr + rstd2*U + cadd (prev layer, deferred); y = PReLU(x_new@W1+b1);
//       stats1 -> gs; nb==0 writes x_new f32 to xw.
__global__ __launch_bounds__(256) void k_ka(
    const float* __restrict__ xr, float* __restrict__ xw,
    const float* __restrict__ U, const float* __restrict__ gsPrev,
    const float* __restrict__ c2bPrev, const float* __restrict__ ccPrev,
    const ushort* __restrict__ w1p, const float* __restrict__ bias,
    const float* __restrict__ pa, ushort* __restrict__ yb,
    float* __restrict__ gs, int hasU)
{
  __shared__ float red[8];
  int tid = threadIdx.x;
  int wv = tid >> 6, l = tid & 63;
  int b = blockIdx.z, mt = blockIdx.y, nb = blockIdx.x;
  int row0 = mt*64 + wv*16;
  int lm = l & 15, lq = l >> 4;
  int row = row0 + lm;
  bool rok = row < T_;
  size_t rbase = ((size_t)b*T_ + row)*256;
  float rstd2 = 0.f, mr = 0.f;
  if (hasU){
    const float icnt = 1.f/((float)T_*(float)H_);
    float m2 = gsPrev[b*2]*icnt;
    rstd2 = rsqrtf(gsPrev[b*2+1]*icnt - m2*m2 + MEPS);
    mr = m2*rstd2;
  }
  int n0 = nb*64;
  f32x4 acc[4] = {};
  #pragma unroll 2
  for (int kc = 0; kc < 8; kc++){
    int k0 = kc*32 + lq*8;
    float xv[8];
    *(float4*)&xv[0] = *(const float4*)(xr + rbase + k0);
    *(float4*)&xv[4] = *(const float4*)(xr + rbase + k0 + 4);
    if (hasU){
      float uv[8], cb[8], c1v[8], c2v[8];
      *(float4*)&uv[0]  = *(const float4*)(U + rbase + k0);
      *(float4*)&uv[4]  = *(const float4*)(U + rbase + k0 + 4);
      *(float4*)&cb[0]  = *(const float4*)(c2bPrev + k0);
      *(float4*)&cb[4]  = *(const float4*)(c2bPrev + k0 + 4);
      *(float4*)&c1v[0] = *(const float4*)(ccPrev + k0);
      *(float4*)&c1v[4] = *(const float4*)(ccPrev + k0 + 4);
      *(float4*)&c2v[0] = *(const float4*)(ccPrev + 256 + k0);
      *(float4*)&c2v[4] = *(const float4*)(ccPrev + 256 + k0 + 4);
      #pragma unroll
      for (int j = 0; j < 8; j++)
        xv[j] = xv[j] + rstd2*uv[j] + cb[j] + c1v[j] - mr*c2v[j];
      if (nb == 0 && rok){
        *(float4*)(xw + rbase + k0)     = *(float4*)&xv[0];
        *(float4*)(xw + rbase + k0 + 4) = *(float4*)&xv[4];
      }
    }
    bf16x8 a;
    #pragma unroll
    for (int j = 0; j < 8; j++) a[j] = (short)f2bf(xv[j]);
    #pragma unroll
    for (int nt = 0; nt < 4; nt++){
      bf16x8 bf = *(const bf16x8*)(w1p + (((size_t)kc*32 + (n0>>4) + nt)*64 + l)*8);
      acc[nt] = __builtin_amdgcn_mfma_f32_16x16x32_bf16(a, bf, acc[nt], 0, 0, 0);
    }
  }
  float ps = 0.f, pss = 0.f;
  #pragma unroll
  for (int nt = 0; nt < 4; nt++){
    int col = n0 + nt*16 + lm;
    float bb = bias[col], pav = pa[col];
    #pragma unroll
    for (int r = 0; r < 4; r++){
      int t = row0 + lq*4 + r;
      if (t < T_){
        float v = acc[nt][r] + bb;
        float p = fmaxf(v, 0.f) + pav*fminf(v, 0.f);
        yb[((size_t)b*T_ + t)*512 + col] = f2bf(p);
        ps += p; pss += p*p;
      }
    }
  }
  #pragma unroll
  for (int off = 32; off > 0; off >>= 1){
    ps  += __shfl_down(ps, off);
    pss += __shfl_down(pss, off);
  }
  if (l == 0){ red[wv*2] = ps; red[wv*2+1] = pss; }
  __syncthreads();
  if (tid == 0) atomicAdd(&gs[b*2],   red[0]+red[2]+red[4]+red[6]);
  if (tid == 1) atomicAdd(&gs[b*2+1], red[1]+red[3]+red[5]+red[7]);
}

// k_kb: recompute p2 = PReLU2(dwconv(gLN1affine(y))) inline per A-fragment;
//       U = p2 @ (g2 (.) W2); nb==0 accumulates stats2(p2) -> gs2.
__global__ __launch_bounds__(256) void k_kb(
    const ushort* __restrict__ yb, const ushort* __restrict__ w2p,
    const float* __restrict__ dwk, const float* __restrict__ gg,
    const float* __restrict__ gb, const float* __restrict__ gs1,
    const float* __restrict__ pa, float* __restrict__ U,
    float* __restrict__ gs2, int dil)
{
  __shared__ float red[8];
  int tid = threadIdx.x;
  int wv = tid >> 6, l = tid & 63;
  int b = blockIdx.z, mt = blockIdx.y, nb = blockIdx.x;
  int row0 = mt*64 + wv*16;
  int lm = l & 15, lq = l >> 4;
  int t = row0 + lm;
  bool rok = t < T_;
  const float icnt = 1.f/((float)T_*(float)H_);
  float m1 = gs1[b*2]*icnt;
  float rstd1 = rsqrtf(gs1[b*2+1]*icnt - m1*m1 + MEPS);
  int n0 = nb*32;
  f32x4 acc[2] = {};
  float sp = 0.f, spp = 0.f;
  const bool dostat = (nb == 0) && rok;
  #pragma unroll 2
  for (int kc = 0; kc < 16; kc++){
    int ch0 = kc*32 + lq*8;
    float ga[8], ba[8];
    {
      float g8[8], b8[8];
      *(float4*)&g8[0] = *(const float4*)(gg + ch0);
      *(float4*)&g8[4] = *(const float4*)(gg + ch0 + 4);
      *(float4*)&b8[0] = *(const float4*)(gb + ch0);
      *(float4*)&b8[4] = *(const float4*)(gb + ch0 + 4);
      #pragma unroll
      for (int j = 0; j < 8; j++){ ga[j] = g8[j]*rstd1; ba[j] = b8[j] - m1*ga[j]; }
    }
    float z[8] = {0.f,0.f,0.f,0.f,0.f,0.f,0.f,0.f};
    #pragma unroll
    for (int kk = 0; kk < 3; kk++){
      int tt = t + (kk-1)*dil;
      if (tt >= 0 && tt < T_){
        bf16x8 yv = *(const bf16x8*)(yb + ((size_t)b*T_ + tt)*512 + ch0);
        float d8[8];
        *(float4*)&d8[0] = *(const float4*)(dwk + kk*H_ + ch0);
        *(float4*)&d8[4] = *(const float4*)(dwk + kk*H_ + ch0 + 4);
        #pragma unroll
        for (int j = 0; j < 8; j++)
          z[j] = fmaf(d8[j], bf2f((ushort)yv[j])*ga[j] + ba[j], z[j]);
      }
    }
    float pa8[8];
    *(float4*)&pa8[0] = *(const float4*)(pa + ch0);
    *(float4*)&pa8[4] = *(const float4*)(pa + ch0 + 4);
    bf16x8 a;
    #pragma unroll
    for (int j = 0; j < 8; j++){
      float p = fmaxf(z[j], 0.f) + pa8[j]*fminf(z[j], 0.f);
      if (dostat){ sp += p; spp += p*p; }
      a[j] = (short)f2bf(p);
    }
    #pragma unroll
    for (int nt = 0; nt < 2; nt++){
      bf16x8 bf = *(const bf16x8*)(w2p + (((size_t)kc*16 + (n0>>4) + nt)*64 + l)*8);
      acc[nt] = __builtin_amdgcn_mfma_f32_16x16x32_bf16(a, bf, acc[nt], 0, 0, 0);
    }
  }
  #pragma unroll
  for (int nt = 0; nt < 2; nt++){
    int col = n0 + nt*16 + lm;
    #pragma unroll
    for (int r = 0; r < 4; r++){
      int tr = row0 + lq*4 + r;
      if (tr < T_) U[((size_t)b*T_ + tr)*256 + col] = acc[nt][r];
    }
  }
  if (nb == 0){
    #pragma unroll
    for (int off = 32; off > 0; off >>= 1){
      sp  += __shfl_down(sp, off);
      spp += __shfl_down(spp, off);
    }
    if (l == 0){ red[wv*2] = sp; red[wv*2+1] = spp; }
    __syncthreads();
    if (tid == 0) atomicAdd(&gs2[b*2],   red[0]+red[2]+red[4]+red[6]);
    if (tid == 1) atomicAdd(&gs2[b*2+1], red[1]+red[3]+red[5]+red[7]);
  }
}

// final deferred apply after layer 31
__global__ __launch_bounds__(256) void k_applyx(
    const float* __restrict__ xr, const float* __restrict__ U,
    const float* __restrict__ gs, const float* __restrict__ c2b,
    const float* __restrict__ cc, float* __restrict__ xo)
{
  int i = blockIdx.x*256 + threadIdx.x;
  if (i < B_*T_*256){
    int b = i / (T_*256);
    int k = i & 255;
    const float icnt = 1.f/((float)T_*(float)H_);
    float m = gs[b*2]*icnt;
    float rstd = rsqrtf(gs[b*2+1]*icnt - m*m + MEPS);
    float mr = m*rstd;
    xo[i] = xr[i] + rstd*U[i] + c2b[k] + cc[k] - mr*cc[256 + k];
  }
}

// ---------------- cLN over [enc | log1p(mag)] ----------------
__global__ __launch_bounds__(256) void k_cln(
    const float* __restrict__ cf,
    const float* __restrict__ gamma, const float* __restrict__ beta,
    float* __restrict__ mag, float* __restrict__ cosp, float* __restrict__ sinp,
    float* __restrict__ xln){
  int t = blockIdx.x, b = blockIdx.y, tid = threadIdx.x;
  size_t row = (size_t)b*T_ + t;
  __shared__ float feat[FC];
  __shared__ float red[8];
  feat[tid] = cf[row*FRSTR + tid];
  if (tid < NFREQ){
    float re = cf[row*FRSTR + 256 + tid], im = cf[row*FRSTR + 385 + tid];
    float m = sqrtf(re*re + im*im);
    mag[row*NFREQ + tid] = m;
    float c = 1.f, s = 0.f;
    if (m > 0.f){ c = re/m; s = im/m; }
    cosp[row*NFREQ + tid] = c;
    sinp[row*NFREQ + tid] = s;
    feat[AE + tid] = log1pf(m);
  }
  __syncthreads();
  float v = feat[tid] + ((tid < FC-256) ? feat[256+tid] : 0.f);
  #pragma unroll
  for (int off = 32; off > 0; off >>= 1) v += __shfl_down(v, off);
  if ((tid & 63) == 0) red[tid>>6] = v;
  __syncthreads();
  float mean = (red[0]+red[1]+red[2]+red[3]) * (1.0f/FC);
  float d0 = feat[tid] - mean;
  float vv = d0*d0;
  if (tid < FC-256){ float d1 = feat[256+tid] - mean; vv += d1*d1; }
  __syncthreads();
  #pragma unroll
  for (int off = 32; off > 0; off >>= 1) vv += __shfl_down(vv, off);
  if ((tid & 63) == 0) red[tid>>6] = vv;
  __syncthreads();
  float var = (red[0]+red[1]+red[2]+red[3]) * (1.0f/FC);
  float rstd = rsqrtf(var + MEPS);
  xln[row*XSTR + tid] = (feat[tid]-mean)*rstd*gamma[tid] + beta[tid];
  if (tid < FC-256)
    xln[row*XSTR + 256+tid] = (feat[256+tid]-mean)*rstd*gamma[256+tid] + beta[256+tid];
  if (tid < XSTR-FC) xln[row*XSTR + FC + tid] = 0.f;
}

// ---------------- attractor accumulation ------------
#define ATTR_CH 16
__global__ __launch_bounds__(256) void k_attr2(const float* __restrict__ emb,
                                               const float* __restrict__ anchors,
                                               float* __restrict__ acc){
  const int c0a[16] = {0,0,0,0,0,1,1,1,1,2,2,2,3,3,4,0};
  const int c1a[16] = {1,2,3,4,5,2,3,4,5,3,4,5,4,5,5,0};
  int by = blockIdx.y;
  int b = by >> 2, g = by & 3;
  int tid = threadIdx.x;
  __shared__ float anc[6][20];
  __shared__ float wred[4][84];
  if (tid < 120) anc[tid/20][tid%20] = anchors[tid];
  __syncthreads();
  float ar[4][21];
  #pragma unroll
  for (int q = 0; q < 4; q++)
    #pragma unroll
    for (int e = 0; e < 21; e++) ar[q][e] = 0.f;
  const float* eb = emb + (size_t)b*KB*EMBED;
  for (int k = blockIdx.x*256 + tid; k < KB; k += ATTR_CH*256){
    float e[20];
    const float4* p = (const float4*)(eb + (size_t)k*EMBED);
    #pragma unroll
    for (int i = 0; i < 5; i++){
      float4 v = p[i];
      e[4*i] = v.x; e[4*i+1] = v.y; e[4*i+2] = v.z; e[4*i+3] = v.w;
    }
    float d[6];
    #pragma unroll
    for (int c = 0; c < 6; c++){
      float s = 0.f;
      #pragma unroll
      for (int j = 0; j < 20; j++) s = fmaf(e[j], anc[c][j], s);
      d[c] = s;
    }
    #pragma unroll
    for (int q = 0; q < 4; q++){
      int s = g*4 + q;
      float w = (s == 15) ? 1.0f : 1.0f / (1.0f + expf(d[c1a[s]] - d[c0a[s]]));
      #pragma unroll
      for (int j = 0; j < 20; j++) ar[q][j] = fmaf(w, e[j], ar[q][j]);
      ar[q][20] += w;
    }
  }
  #pragma unroll
  for (int q = 0; q < 4; q++)
    #pragma unroll
    for (int e = 0; e < 21; e++)
      #pragma unroll
      for (int off = 32; off > 0; off >>= 1)
        ar[q][e] += __shfl_down(ar[q][e], off);
  if ((tid & 63) == 0){
    int w = tid >> 6;
    #pragma unroll
    for (int q = 0; q < 4; q++)
      #pragma unroll
      for (int e = 0; e < 21; e++) wred[w][q*21+e] = ar[q][e];
  }
  __syncthreads();
  if (tid < 84){
    float s = wred[0][tid] + wred[1][tid] + wred[2][tid] + wred[3][tid];
    int q = tid / 21, e = tid % 21;
    atomicAdd(&acc[((size_t)b*16 + g*4 + q)*21 + e], s);
  }
}

// ---------------- attractor normalize + select ----------------
__global__ __launch_bounds__(128) void k_attrfin2(const float* __restrict__ acc,
                                                  float* __restrict__ attractors){
  __shared__ float aN[120][40];
  __shared__ float sp[120];
  int tid = threadIdx.x;
  if (tid < 120){
    int b = tid / 15, p = tid % 15;
    const float* ap = acc + ((size_t)b*16 + p)*21;
    const float* ae = acc + ((size_t)b*16 + 15)*21;
    float den0 = ap[20];
    float den1 = (float)KB - den0;
    float s = 0.f;
    for (int e = 0; e < 20; e++){
      float a0 = ap[e] / den0;
      float a1 = (ae[e] - ap[e]) / den1;
      aN[tid][e] = a0; aN[tid][20+e] = a1;
      s = fmaf(a0, a1, s);
    }
    sp[tid] = s;
  }
  __syncthreads();
  if (tid < B_){
    int base = tid * 15, best = 0;
    float bv = sp[base];
    for (int p = 1; p < 15; p++) if (sp[base+p] < bv){ bv = sp[base+p]; best = p; }
    for (int i = 0; i < 40; i++) attractors[tid*40 + i] = aN[base+best][i];
  }
}

// ---------------- build decoder-GEMM A rows (stride 516, pads zeroed) -------
__global__ __launch_bounds__(256) void k_afull(
    const float* __restrict__ emb, const float* __restrict__ cf,
    const float* __restrict__ mag, const float* __restrict__ cosp,
    const float* __restrict__ sinp, const float* __restrict__ attractors,
    float* __restrict__ Af){
  int t = blockIdx.x, b = blockIdx.y, tid = threadIdx.x;
  __shared__ float att[40];
  if (tid < 40) att[tid] = attractors[b*40 + tid];
  __syncthreads();
  size_t row = (size_t)b*T_ + t;
  size_t r0 = ((size_t)(b*2+0)*T_ + t)*AFSTR;
  size_t r1 = ((size_t)(b*2+1)*T_ + t)*AFSTR;
  for (int f = tid; f < FC; f += 256){
    const float* e = emb + (row*FC + f)*20;
    float l0 = 0.f, l1 = 0.f;
    #pragma unroll
    for (int j = 0; j < 20; j++){
      float ev = e[j];
      l0 = fmaf(ev, att[j],    l0);
      l1 = fmaf(ev, att[20+j], l1);
    }
    if (f < AE){
      float ft = cf[row*FRSTR + f];
      Af[r0 + f] = l0*ft;
      Af[r1 + f] = l1*ft;
    } else {
      int fi = f - AE;
      float ft = mag[row*NFREQ + fi];
      float c = cosp[row*NFREQ + fi], s = sinp[row*NFREQ + fi];
      float s0 = l0*ft, s1v = l1*ft;
      Af[r0 + 256 + fi] = c*s0;  Af[r0 + 385 + fi] = s*s0;
      Af[r1 + 256 + fi] = c*s1v; Af[r1 + 385 + fi] = s*s1v;
    }
  }
  if (tid < 2){
    Af[r0 + 514 + tid] = 0.f;
    Af[r1 + 514 + tid] = 0.f;
  }
}

// ---------------- overlap-add gather ----------------
__global__ __launch_bounds__(256) void k_ola(const float* __restrict__ frames,
                                             float* __restrict__ out){
  int i = blockIdx.x*256 + threadIdx.x;
  if (i < B_*2*L_){
    int bs = i / L_, l = i % L_;
    int t0 = l >> 6;
    float s = 0.f;
    #pragma unroll
    for (int j = 0; j < 4; j++){
      int t = t0 - j;
      if (t >= 0 && t < T_){
        int k = l - t*64;
        s += frames[((size_t)bs*T_ + t)*256 + k];
      }
    }
    out[i] = s;
  }
}

// ---------------- launcher ----------------
extern "C" void kernel_launch(void* const* d_in, const int* in_sizes, int n_in,
                              void* d_out, int out_size, void* d_ws, size_t ws_size,
                              hipStream_t stream) {
  const float* audios   = (const float*)d_in[0];
  const float* enc_w    = (const float*)d_in[1];
  const float* enc_b    = (const float*)d_in[2];
  const float* bgamma   = (const float*)d_in[3];
  const float* bbeta    = (const float*)d_in[4];
  const float* bottle_w = (const float*)d_in[5];
  const float* bottle_b = (const float*)d_in[6];
  const float* c1_w     = (const float*)d_in[7];
  const float* c1_b     = (const float*)d_in[8];
  const float* p1       = (const float*)d_in[9];
  const float* g1_g     = (const float*)d_in[10];
  const float* g1_b     = (const float*)d_in[11];
  const float* dwp      = (const float*)d_in[12];
  const float* p2       = (const float*)d_in[13];
  const float* g2_g     = (const float*)d_in[14];
  const float* g2_b     = (const float*)d_in[15];
  const float* c2_w     = (const float*)d_in[16];
  const float* c2_b     = (const float*)d_in[17];
  const float* sep_w    = (const float*)d_in[18];
  const float* sep_b    = (const float*)d_in[19];
  const float* anchors  = (const float*)d_in[20];
  const float* dec_w    = (const float*)d_in[21];
  const float* dec_b    = (const float*)d_in[22];

  float* ws = (float*)d_ws;
  float* bfr   = ws + o_bfr;
  float* decB  = ws + o_decB;
  float* decBias = ws + o_decBias;
  float* biasF = ws + o_biasF;
  float* cf    = ws + o_cf;
  float* mag   = ws + o_mag;
  float* cosp  = ws + o_cosp;
  float* sinp  = ws + o_sinp;
  float* xln   = ws + o_xln;
  float* xbuf0 = ws + o_x;
  float* xbuf1 = ws + o_y;                         // first half of o_y region
  float* Ubuf  = ws + o_y + (size_t)B_*T_*BTL;     // second half
  float* gsum  = ws + o_gsum;
  float* accp  = ws + o_acc;
  float* attp  = ws + o_att;
  float* embp  = ws + o_emb;
  float* Afull = ws + o_Af;
  float* framesp = ws + o_fr;
  float* c1c2  = ws + o_c1c2;
  ushort* w1p  = (ushort*)(ws + o_w1p);
  ushort* w2p  = (ushort*)(ws + o_w2p);
  ushort* yb16 = (ushort*)(ws + o_z);

  // zero atomic accumulators (gsum 1024 + attr acc 2688, contiguous) and c1c2
  hipMemsetAsync((void*)gsum, 0, (1024 + (size_t)B_*16*21) * sizeof(float), stream);
  hipMemsetAsync((void*)c1c2, 0, (size_t)32*512*sizeof(float), stream);

  k_setup<<<PREP_BLOCKS + PACKW_BLOCKS + BIAS2_BLOCKS, 256, 0, stream>>>(
      enc_w, enc_b, dec_w, dec_b, c1_w, c2_w, g2_g, g2_b,
      bfr, decB, decBias, biasF, w1p, w2p, c1c2);

  // frames GEMM: mix-on-load, [enc | spec] out, M=3976, N=516, K=256
  gemm3<2><<<dim3(9, 63), 256, 0, stream>>>(
      audios, bfr, biasF, cf, B_*T_, FRSTR, 256, 0, FRSTR, 256);

  k_cln<<<dim3(T_, B_), 256, 0, stream>>>(cf, bgamma, bbeta, mag, cosp, sinp, xln);

  // bottleneck -> x(0) in buf0
  gemm3<0><<<dim3(4, 63), 256, 0, stream>>>(
      xln, bottle_w, bottle_b, xbuf0, B_*T_, BTL, FC, XSTR, BTL, 0);

  // TCN: 2 kernels per layer; deferred c2-apply folded into next layer's A-load
  float* bufs[2] = { xbuf0, xbuf1 };
  for (int i = 0; i < NB; i++){
    int dil = 1 << (i & 7);
    const float* xr = (i == 0) ? xbuf0 : bufs[(i-1) & 1];
    float* xw = bufs[i & 1];
    const float* gsPrev = (i == 0) ? gsum : (gsum + (i-1)*32 + 16);
    const float* c2bPrev = c2_b + (size_t)((i > 0) ? (i-1) : 0)*BTL;
    const float* ccPrev  = c1c2 + (size_t)((i > 0) ? (i-1) : 0)*512;
    k_ka<<<dim3(8, 8, B_), 256, 0, stream>>>(
        xr, xw, Ubuf, gsPrev, c2bPrev, ccPrev,
        w1p + (size_t)i*131072, c1_b + i*H_, p1 + i*H_,
        yb16, gsum + i*32, (i > 0) ? 1 : 0);
    k_kb<<<dim3(8, 8, B_), 256, 0, stream>>>(
        yb16, w2p + (size_t)i*131072, dwp + (size_t)i*3*H_,
        g1_g + i*H_, g1_b + i*H_, gsum + i*32, p2 + i*H_,
        Ubuf, gsum + i*32 + 16, dil);
  }
  // final apply: x_final = x(31) + rstd2*U(31) + cadd(31) -> buf0 (x(31) is in buf1)
  k_applyx<<<(B_*T_*256 + 255)/256, 256, 0, stream>>>(
      bufs[(NB-1) & 1], Ubuf, gsum + (NB-1)*32 + 16,
      c2_b + (size_t)(NB-1)*BTL, c1c2 + (size_t)(NB-1)*512, xbuf0);

  // separator: M=3976, N=7700, K=256
  gemm2<<<dim3(121, 32), 256, 0, stream>>>(
      xbuf0, sep_w, sep_b, embp, B_*T_, FC*EMBED, BTL, BTL);

  // attractors
  k_attr2<<<dim3(ATTR_CH, B_*4), 256, 0, stream>>>(embp, anchors, accp);
  k_attrfin2<<<1, 128, 0, stream>>>(accp, attp);

  // decode: M=7952, N=256, K=514 (lda=516, zero-padded)
  k_afull<<<dim3(T_, B_), 256, 0, stream>>>(embp, cf, mag, cosp, sinp, attp, Afull);
  gemm3<0><<<dim3(4, 125), 256, 0, stream>>>(
      Afull, decB, decBias, framesp, 2*B_*T_, 256, 514, AFSTR, BTL, 0);
  k_ola<<<(B_*2*L_ + 255)/256, 256, 0, stream>>>(framesp, (float*)d_out);
}